// Round 8
// baseline (1111.623 us; speedup 1.0000x reference)
//
#include <hip/hip_runtime.h>
#include <stdint.h>

// ---------------------------------------------------------------------------
// KeypointMatchingModel: B=8, N=128, C_IN=C_OUT=512, H_MLP=128, STEPS=10.
// R2 fp32: 2254us. R3: 1475us. R4: 1890us (LN grid bug). R5: 1022us.
// R6: 1040us (NEUTRAL). R7: FAILED -- split-K P GEMM used BIASM (bias[node],
// OOB on fbm[128]) instead of BIASN (bias[h]). R8 = R7 with BIASN gated on
// split-K chunk 0 and the P call restored to BIASN=1.
//   - agg GEMM epilogue fuses +Y_right +rb, relu, AGGt(fp32) store, and
//     per-node sum/sumsq (LDS atomics -> global atomics partS/partQ[2048]).
//   - P GEMM split-K x4 (grid 256 blocks, fp32 atomicAdd, bias on chunk 0).
//   - partS/partQ/Pt zeroed inside mfma_gemm_big (no extra launch).
// Per-iter kernels: tail, R_t, G1, agg_fused, ln_apply, P = 6.
// RNG: jax threefry partitionable, bits = o0^o1 of block(key, 0, i). VERIFIED.
// ---------------------------------------------------------------------------

typedef unsigned short u16;
typedef unsigned int u32;
typedef __attribute__((ext_vector_type(8))) short short8;
typedef __attribute__((ext_vector_type(4))) float f32x4;

__device__ inline u16 f2bf(float x) {
  u32 u = __float_as_uint(x);
  u32 r = (u + 0x7fffu + ((u >> 16) & 1u)) >> 16;  // round-nearest-even
  return (u16)r;
}
__device__ inline float bf2f(u16 h) { return __uint_as_float(((u32)h) << 16); }
__device__ inline void split2(float x, u16& h, u16& l) {
  h = f2bf(x);
  l = f2bf(x - bf2f(h));
}

__host__ __device__ inline void tf2x32(uint32_t k0, uint32_t k1, uint32_t x0,
                                       uint32_t x1, uint32_t& o0, uint32_t& o1) {
  uint32_t ks0 = k0, ks1 = k1, ks2 = 0x1BD11BDAu ^ k0 ^ k1;
  x0 += ks0; x1 += ks1;
#define TF_R(r) { x0 += x1; x1 = (x1 << r) | (x1 >> (32 - r)); x1 ^= x0; }
  TF_R(13) TF_R(15) TF_R(26) TF_R(6)   x0 += ks1; x1 += ks2 + 1u;
  TF_R(17) TF_R(29) TF_R(16) TF_R(24)  x0 += ks2; x1 += ks0 + 2u;
  TF_R(13) TF_R(15) TF_R(26) TF_R(6)   x0 += ks0; x1 += ks1 + 3u;
  TF_R(17) TF_R(29) TF_R(16) TF_R(24)  x0 += ks1; x1 += ks2 + 4u;
  TF_R(13) TF_R(15) TF_R(26) TF_R(6)   x0 += ks2; x1 += ks0 + 5u;
#undef TF_R
  o0 = x0; o1 = x1;
}

__device__ inline float erfinv_f(float x) {  // XLA ErfInv32 (Giles)
  float w = -log1pf(-x * x);
  float p;
  if (w < 5.0f) {
    w = w - 2.5f;
    p = 2.81022636e-08f;
    p = fmaf(p, w, 3.43273939e-07f);
    p = fmaf(p, w, -3.5233877e-06f);
    p = fmaf(p, w, -4.39150654e-06f);
    p = fmaf(p, w, 0.00021858087f);
    p = fmaf(p, w, -0.00125372503f);
    p = fmaf(p, w, -0.00417768164f);
    p = fmaf(p, w, 0.246640727f);
    p = fmaf(p, w, 1.50140941f);
  } else {
    w = sqrtf(w) - 3.0f;
    p = -0.000200214257f;
    p = fmaf(p, w, 0.000100950558f);
    p = fmaf(p, w, 0.00134934322f);
    p = fmaf(p, w, -0.00367342844f);
    p = fmaf(p, w, 0.00573950773f);
    p = fmaf(p, w, -0.0076224613f);
    p = fmaf(p, w, 0.00943887047f);
    p = fmaf(p, w, 1.00167406f);
    p = fmaf(p, w, 2.83297682f);
  }
  return p * x;
}

__device__ inline float bits_to_normal(uint32_t bits) {
  uint32_t fb = (bits >> 9) | 0x3f800000u;
  float f = __uint_as_float(fb) - 1.0f;
  float u = f * 2.0f + (-0.99999994f);
  u = fmaxf(-0.99999994f, u);
  return 1.41421356f * erfinv_f(u);
}

// ---------------------------------------------------------------------------
// 64x64-tile split-bf16 MFMA GEMM. D = A @ B^T, stores D^T.
// OUTP: bf16-plane output; AGGB: Yt-gather B; RELULN: fused relu+rb+LN-stats
// epilogue (agg); ATOMIC: split-K fp32 atomicAdd output (blockIdx.z = chunk,
// biases applied only on chunk 0).
// ---------------------------------------------------------------------------
template <int OUTP, int BIASN, int BIASM, int AGGB, int RELULN, int ATOMIC>
__global__ __launch_bounds__(256) void mfma_gemm(
    int K,
    const u16* __restrict__ Ah, const u16* __restrict__ Al, int lda, int sA,
    const u16* __restrict__ Bh, const u16* __restrict__ Bl, int ldb, int sB,
    float* __restrict__ Cf, u16* __restrict__ Ch, u16* __restrict__ Cl,
    int ldc, int sC, const float* __restrict__ bias,
    const u16* __restrict__ Y2h, const u16* __restrict__ Y2l,
    const float* __restrict__ rb2, float* __restrict__ pS,
    float* __restrict__ pQ) {
  const int g = blockIdx.z;
  Ah += (size_t)g * sA; Al += (size_t)g * sA;
  Bh += (size_t)g * sB; Bl += (size_t)g * sB;
  if (OUTP) { Ch += (size_t)g * sC; Cl += (size_t)g * sC; }
  else { Cf += (size_t)g * sC; }
  __shared__ u16 As[2][64][64];
  __shared__ u16 Bs[2][64][64];
  __shared__ float s_lds[64], q_lds[64];
  const int tid = threadIdx.x;
  const int m0 = blockIdx.y * 64, n0 = blockIdx.x * 64;
  const int l = tid & 63;
  const int w = tid >> 6;
  const int wr = (w >> 1) * 32, wc = (w & 1) * 32;
  const int l15 = l & 15, lq = l >> 4;
  f32x4 acc[2][2] = {};
  const int sr = tid >> 3, sc = tid & 7;
  if (RELULN && tid < 64) { s_lds[tid] = 0.f; q_lds[tid] = 0.f; }
  for (int k0 = 0; k0 < K; k0 += 64) {
    __syncthreads();
#pragma unroll
    for (int p = 0; p < 2; ++p) {
      int r = sr + p * 32;
      int dst = (sc ^ (r & 7)) * 8;
      *(uint4*)&As[0][r][dst] = *(const uint4*)&Ah[(size_t)(m0 + r) * lda + k0 + sc * 8];
      *(uint4*)&As[1][r][dst] = *(const uint4*)&Al[(size_t)(m0 + r) * lda + k0 + sc * 8];
      size_t boff;
      if (AGGB) {
        int rowg = (k0 < 128) ? (n0 + r) : (512 + n0 + r);
        boff = (size_t)rowg * ldb + (k0 & 127) + sc * 8;
      } else {
        boff = (size_t)(n0 + r) * ldb + k0 + sc * 8;
      }
      *(uint4*)&Bs[0][r][dst] = *(const uint4*)&Bh[boff];
      *(uint4*)&Bs[1][r][dst] = *(const uint4*)&Bl[boff];
    }
    __syncthreads();
#pragma unroll
    for (int kk = 0; kk < 2; ++kk) {
      short8 aH[2], aL[2], bH[2], bL[2];
#pragma unroll
      for (int i = 0; i < 2; ++i) {
        int mr = wr + i * 16 + l15;
        int ca = ((kk * 4 + lq) ^ (mr & 7)) * 8;
        aH[i] = *(const short8*)&As[0][mr][ca];
        aL[i] = *(const short8*)&As[1][mr][ca];
        int nr = wc + i * 16 + l15;
        int cb = ((kk * 4 + lq) ^ (nr & 7)) * 8;
        bH[i] = *(const short8*)&Bs[0][nr][cb];
        bL[i] = *(const short8*)&Bs[1][nr][cb];
      }
#pragma unroll
      for (int i = 0; i < 2; ++i)
#pragma unroll
        for (int j = 0; j < 2; ++j) {
          acc[i][j] = __builtin_amdgcn_mfma_f32_16x16x32_bf16(aH[i], bH[j], acc[i][j], 0, 0, 0);
          acc[i][j] = __builtin_amdgcn_mfma_f32_16x16x32_bf16(aL[i], bH[j], acc[i][j], 0, 0, 0);
          acc[i][j] = __builtin_amdgcn_mfma_f32_16x16x32_bf16(aH[i], bL[j], acc[i][j], 0, 0, 0);
        }
    }
  }
  float sv[2][4] = {}, qv[2][4] = {};
#pragma unroll
  for (int i = 0; i < 2; ++i)
#pragma unroll
    for (int j = 0; j < 2; ++j) {
      int n = n0 + wc + j * 16 + l15;
      int mb = m0 + wr + i * 16 + lq * 4;
      f32x4 v = acc[i][j];
      if (BIASN && (!ATOMIC || g == 0)) {   // R8 fix: gate BIASN on chunk 0
        float b = bias[n];
        v[0] += b; v[1] += b; v[2] += b; v[3] += b;
      }
      if (BIASM && (!ATOMIC || g == 0)) {
        f32x4 bb = *(const f32x4*)&bias[mb];
        v[0] += bb[0]; v[1] += bb[1]; v[2] += bb[2]; v[3] += bb[3];
      }
      if (RELULN) {
        // add Y_right + rb, relu; accumulate per-node partial sums
        int gm = g * 128 + mb;   // absolute node
        float rbn = rb2[n];
        uint2 yh = *(const uint2*)&Y2h[(size_t)(1024 + n) * 2048 + gm];
        uint2 yl = *(const uint2*)&Y2l[(size_t)(1024 + n) * 2048 + gm];
        v[0] = fmaxf(v[0] + bf2f((u16)(yh.x & 0xffff)) + bf2f((u16)(yl.x & 0xffff)) + rbn, 0.f);
        v[1] = fmaxf(v[1] + bf2f((u16)(yh.x >> 16)) + bf2f((u16)(yl.x >> 16)) + rbn, 0.f);
        v[2] = fmaxf(v[2] + bf2f((u16)(yh.y & 0xffff)) + bf2f((u16)(yl.y & 0xffff)) + rbn, 0.f);
        v[3] = fmaxf(v[3] + bf2f((u16)(yh.y >> 16)) + bf2f((u16)(yl.y >> 16)) + rbn, 0.f);
#pragma unroll
        for (int r = 0; r < 4; ++r) {
          sv[i][r] += v[r];
          qv[i][r] += v[r] * v[r];
        }
        *(f32x4*)&Cf[(size_t)n * ldc + mb] = v;
      } else if (ATOMIC) {
#pragma unroll
        for (int r = 0; r < 4; ++r)
          atomicAdd(&Cf[(size_t)n * ldc + mb + r], v[r]);
      } else if (OUTP) {
        u16 h[4], lo[4];
        split2(v[0], h[0], lo[0]); split2(v[1], h[1], lo[1]);
        split2(v[2], h[2], lo[2]); split2(v[3], h[3], lo[3]);
        uint2 hv = {(u32)h[0] | ((u32)h[1] << 16), (u32)h[2] | ((u32)h[3] << 16)};
        uint2 lv = {(u32)lo[0] | ((u32)lo[1] << 16), (u32)lo[2] | ((u32)lo[3] << 16)};
        *(uint2*)&Ch[(size_t)n * ldc + mb] = hv;
        *(uint2*)&Cl[(size_t)n * ldc + mb] = lv;
      } else {
        *(f32x4*)&Cf[(size_t)n * ldc + mb] = v;
      }
    }
  if (RELULN) {
#pragma unroll
    for (int i = 0; i < 2; ++i)
#pragma unroll
      for (int r = 0; r < 4; ++r) {
        int nl = wr + i * 16 + lq * 4 + r;
        atomicAdd(&s_lds[nl], sv[i][r]);
        atomicAdd(&q_lds[nl], qv[i][r]);
      }
    __syncthreads();
    if (tid < 64) {
      atomicAdd(&pS[g * 128 + m0 + tid], s_lds[tid]);
      atomicAdd(&pQ[g * 128 + m0 + tid], q_lds[tid]);
    }
  }
}

// ---------------------------------------------------------------------------
// 128x128-tile split-bf16 MFMA GEMM (G1 and embedding O). Also cooperatively
// zeroes partS/partQ (block 0) and Pt (distributed) for the downstream
// agg_fused / split-K P kernels.
// ---------------------------------------------------------------------------
template <int BIASM>
__global__ __launch_bounds__(512) void mfma_gemm_big(
    int K,
    const u16* __restrict__ Ah, const u16* __restrict__ Al, int lda,
    const u16* __restrict__ Bh, const u16* __restrict__ Bl, int ldb,
    u16* __restrict__ Ch, u16* __restrict__ Cl, int ldc,
    const float* __restrict__ bias, float* __restrict__ pS,
    float* __restrict__ pQ, float* __restrict__ Ptz) {
  __shared__ u16 As[2][128][64];
  __shared__ u16 Bs[2][128][64];
  const int tid = threadIdx.x;
  const int bid = blockIdx.y * gridDim.x + blockIdx.x;
  const int nb = gridDim.x * gridDim.y;
  // zero partS/partQ (block 0) + Pt (distributed f4)
  if (bid == 0) {
    for (int i = tid; i < 2048; i += 512) { pS[i] = 0.f; pQ[i] = 0.f; }
  }
  float4 z4 = {0.f, 0.f, 0.f, 0.f};
  for (int i = bid * 512 + tid; i < 65536; i += nb * 512)
    ((float4*)Ptz)[i] = z4;
  const int m0 = blockIdx.y * 128, n0 = blockIdx.x * 128;
  const int l = tid & 63;
  const int w = tid >> 6;            // 0..7
  const int wm = (w >> 2) * 64;      // 0,64
  const int wn = (w & 3) * 32;       // 0,32,64,96
  const int l15 = l & 15, lq = l >> 4;
  f32x4 acc[4][2] = {};
  const int sr = tid >> 3, sc = tid & 7;   // sr 0..63, sc 0..7
  for (int k0 = 0; k0 < K; k0 += 64) {
    __syncthreads();
#pragma unroll
    for (int p = 0; p < 2; ++p) {
      int r = p * 64 + sr;
      int dst = (sc ^ (r & 7)) * 8;
      *(uint4*)&As[0][r][dst] = *(const uint4*)&Ah[(size_t)(m0 + r) * lda + k0 + sc * 8];
      *(uint4*)&As[1][r][dst] = *(const uint4*)&Al[(size_t)(m0 + r) * lda + k0 + sc * 8];
      *(uint4*)&Bs[0][r][dst] = *(const uint4*)&Bh[(size_t)(n0 + r) * ldb + k0 + sc * 8];
      *(uint4*)&Bs[1][r][dst] = *(const uint4*)&Bl[(size_t)(n0 + r) * ldb + k0 + sc * 8];
    }
    __syncthreads();
#pragma unroll
    for (int kk = 0; kk < 2; ++kk) {
      short8 aH[4], aL[4], bH[2], bL[2];
#pragma unroll
      for (int i = 0; i < 4; ++i) {
        int mr = wm + i * 16 + l15;
        int ca = ((kk * 4 + lq) ^ (mr & 7)) * 8;
        aH[i] = *(const short8*)&As[0][mr][ca];
        aL[i] = *(const short8*)&As[1][mr][ca];
      }
#pragma unroll
      for (int j = 0; j < 2; ++j) {
        int nr = wn + j * 16 + l15;
        int cb = ((kk * 4 + lq) ^ (nr & 7)) * 8;
        bH[j] = *(const short8*)&Bs[0][nr][cb];
        bL[j] = *(const short8*)&Bs[1][nr][cb];
      }
#pragma unroll
      for (int i = 0; i < 4; ++i)
#pragma unroll
        for (int j = 0; j < 2; ++j) {
          acc[i][j] = __builtin_amdgcn_mfma_f32_16x16x32_bf16(aH[i], bH[j], acc[i][j], 0, 0, 0);
          acc[i][j] = __builtin_amdgcn_mfma_f32_16x16x32_bf16(aL[i], bH[j], acc[i][j], 0, 0, 0);
          acc[i][j] = __builtin_amdgcn_mfma_f32_16x16x32_bf16(aH[i], bL[j], acc[i][j], 0, 0, 0);
        }
    }
  }
#pragma unroll
  for (int i = 0; i < 4; ++i)
#pragma unroll
    for (int j = 0; j < 2; ++j) {
      int n = n0 + wn + j * 16 + l15;
      int mb = m0 + wm + i * 16 + lq * 4;
      f32x4 v = acc[i][j];
      if (BIASM) {
        f32x4 bb = *(const f32x4*)&bias[mb];
        v[0] += bb[0]; v[1] += bb[1]; v[2] += bb[2]; v[3] += bb[3];
      }
      u16 h[4], lo[4];
      split2(v[0], h[0], lo[0]); split2(v[1], h[1], lo[1]);
      split2(v[2], h[2], lo[2]); split2(v[3], h[3], lo[3]);
      uint2 hv = {(u32)h[0] | ((u32)h[1] << 16), (u32)h[2] | ((u32)h[3] << 16)};
      uint2 lv = {(u32)lo[0] | ((u32)lo[1] << 16), (u32)lo[2] | ((u32)lo[3] << 16)};
      *(uint2*)&Ch[(size_t)n * ldc + mb] = hv;
      *(uint2*)&Cl[(size_t)n * ldc + mb] = lv;
    }
}

// ---------------- setup kernels ---------------------------------------------
__global__ __launch_bounds__(256) void count_kernel(const int* __restrict__ ei_s,
                                                    const int* __restrict__ ei_t,
                                                    int* __restrict__ Acnt,
                                                    int* __restrict__ degd,
                                                    int* __restrict__ degs) {
  int e = blockIdx.x * 256 + threadIdx.x;        // 32768
  int side = e >> 14, idx = e & 16383;
  const int* ei = side ? ei_t : ei_s;
  int src = ei[idx], dst = ei[16384 + idx];
  int g = (dst >> 7) + side * 8;                 // 0..15
  int dl = dst & 127, sl = src & 127;
  atomicAdd(&Acnt[(g * 128 + dl) * 128 + sl], 1);
  atomicAdd(&degd[g * 128 + dl], 1);
  atomicAdd(&degs[g * 128 + sl], 1);
}

__global__ __launch_bounds__(256) void norm_adj_kernel(const int* __restrict__ Acnt,
                                                       const int* __restrict__ degd,
                                                       const int* __restrict__ degs,
                                                       u16* __restrict__ Mh,
                                                       u16* __restrict__ Ml) {
  int idx = blockIdx.x * 256 + threadIdx.x;      // 16*128*256
  int g = idx >> 15, m = (idx >> 8) & 127, k = idx & 255;
  float val;
  if (k < 128)
    val = (float)Acnt[(g * 128 + m) * 128 + k] / (float)max(degd[g * 128 + m], 1);
  else
    val = (float)Acnt[(g * 128 + (k - 128)) * 128 + m] / (float)max(degs[g * 128 + m], 1);
  u16 h, lo;
  split2(val, h, lo);
  Mh[idx] = h; Ml[idx] = lo;
}

// [W1|W2|Wr]^T hi/lo planes directly: Th[n*512+k], n<512->W1, <1024->W2, else Wr
__global__ __launch_bounds__(256) void convert_packed(const float* __restrict__ W1,
                                                      const float* __restrict__ W2,
                                                      const float* __restrict__ Wr,
                                                      u16* __restrict__ Th,
                                                      u16* __restrict__ Tl) {
  int id = blockIdx.x * 256 + threadIdx.x;       // 1536*512
  int n = id >> 9, k = id & 511;
  const float* W = (n < 512) ? W1 : ((n < 1024) ? W2 : Wr);
  float v = W[k * 512 + (n & 511)];
  u16 h, lo;
  split2(v, h, lo);
  Th[id] = h; Tl[id] = lo;
}

// W [K][N] fp32 -> W^T hi/lo [N][K] bf16
__global__ __launch_bounds__(256) void convert_wT(const float* __restrict__ W,
                                                  u16* __restrict__ Th,
                                                  u16* __restrict__ Tl,
                                                  int K, int N) {
  int id = blockIdx.x * 256 + threadIdx.x;
  int k = id / N, n = id - k * N;
  u16 h, lo;
  split2(W[id], h, lo);
  Th[n * K + k] = h;
  Tl[n * K + k] = lo;
}

// fbm[h] = m_b1[h] + sum_c c_fb[c] * m_w1[c][h]
__global__ __launch_bounds__(128) void fbm_kernel(const float* __restrict__ fb,
                                                  const float* __restrict__ w1,
                                                  const float* __restrict__ b1,
                                                  float* __restrict__ fbm) {
  int h = threadIdx.x;
  float acc = b1[h];
  for (int c = 0; c < 512; ++c) acc = fmaf(fb[c], w1[c * 128 + h], acc);
  fbm[h] = acc;
}

// x_s/x_t -> XH planes (left 512 cols)
__global__ __launch_bounds__(256) void copyx_kernel(const float* __restrict__ xs,
                                                    const float* __restrict__ xt,
                                                    u16* __restrict__ XHh,
                                                    u16* __restrict__ XHl) {
  int idx = blockIdx.x * 256 + threadIdx.x;      // 2048 rows * 128 float4s
  int row = idx >> 7, c4 = (idx & 127) << 2;
  const float* src = (row < 1024) ? (xs + row * 512 + c4)
                                  : (xt + (row - 1024) * 512 + c4);
  float4 v = *(const float4*)src;
  u16 h[4], lo[4];
  split2(v.x, h[0], lo[0]); split2(v.y, h[1], lo[1]);
  split2(v.z, h[2], lo[2]); split2(v.w, h[3], lo[3]);
  uint2 hv = {(u32)h[0] | ((u32)h[1] << 16), (u32)h[2] | ((u32)h[3] << 16)};
  uint2 lv = {(u32)lo[0] | ((u32)lo[1] << 16), (u32)lo[2] | ((u32)lo[3] << 16)};
  *(uint2*)&XHh[row * 1024 + c4] = hv;
  *(uint2*)&XHl[row * 1024 + c4] = lv;
}

// ---------------- fp32 tiled GEMM (setup only: Fm = c_fw @ m_w1) ------------
__global__ __launch_bounds__(256) void gemm_f32(
    int M, int N, int K,
    const float* __restrict__ A, int lda,
    const float* __restrict__ B, int ldb,
    float* __restrict__ C, int ldc) {
  int m0 = blockIdx.y * 64, n0 = blockIdx.x * 64;
  __shared__ float As[16][64];
  __shared__ float Bs[16][64];
  int tid = threadIdx.x;
  int tx = tid & 15, ty = tid >> 4;
  float acc[4][4] = {};
  for (int k0 = 0; k0 < K; k0 += 16) {
    {
      int m_l = tid & 63, k_l = (tid >> 6) << 2;
      float4 av = *(const float4*)&A[(m0 + m_l) * lda + k0 + k_l];
      As[k_l + 0][m_l] = av.x; As[k_l + 1][m_l] = av.y;
      As[k_l + 2][m_l] = av.z; As[k_l + 3][m_l] = av.w;
    }
    {
      int k_l = tid >> 4, n_l = (tid & 15) << 2;
      float4 bv = *(const float4*)&B[(k0 + k_l) * ldb + n0 + n_l];
      *(float4*)&Bs[k_l][n_l] = bv;
    }
    __syncthreads();
#pragma unroll
    for (int kk = 0; kk < 16; ++kk) {
      float4 a4 = *(const float4*)&As[kk][ty << 2];
      float4 b4 = *(const float4*)&Bs[kk][tx << 2];
      float av[4] = {a4.x, a4.y, a4.z, a4.w};
      float bv[4] = {b4.x, b4.y, b4.z, b4.w};
#pragma unroll
      for (int i = 0; i < 4; ++i)
#pragma unroll
        for (int j = 0; j < 4; ++j) acc[i][j] = fmaf(av[i], bv[j], acc[i][j]);
    }
    __syncthreads();
  }
#pragma unroll
  for (int i = 0; i < 4; ++i) {
    int m = m0 + (ty << 2) + i;
    float4 v = {acc[i][0], acc[i][1], acc[i][2], acc[i][3]};
    *(float4*)&C[m * ldc + n0 + (tx << 2)] = v;
  }
}

// ---- LN apply: reads activated AGGt + partS/partQ, LDS transpose, XH write -
__global__ __launch_bounds__(256) void ln_apply(
    const float* __restrict__ AGGt, const float* __restrict__ pS,
    const float* __restrict__ pQ, const float* __restrict__ gam,
    const float* __restrict__ bet, u16* __restrict__ XHh,
    u16* __restrict__ XHl) {
  int cg = blockIdx.x, ng = blockIdx.y;
  int lane = threadIdx.x & 63, cs = threadIdx.x >> 6;
  int node = ng * 64 + lane;
  float s = pS[node], q = pQ[node];
  float mu = s * (1.f / 512.f);
  float var = q * (1.f / 512.f) - mu * mu;
  float inv = 1.f / sqrtf(var + 1e-5f);
  __shared__ u16 oth[64][66], otl[64][66];   // +2 pad: conflict-free col writes
#pragma unroll
  for (int k = 0; k < 16; ++k) {
    int c = cg * 64 + cs * 16 + k;
    float v = AGGt[(size_t)c * 2048 + node];
    float o = (v - mu) * inv * gam[c] + bet[c];
    u16 h, lo;
    split2(o, h, lo);
    oth[lane][cs * 16 + k] = h;
    otl[lane][cs * 16 + k] = lo;
  }
  __syncthreads();
  int nl = threadIdx.x >> 2, cq = (threadIdx.x & 3) * 16;
  size_t xbase = (size_t)(ng * 64 + nl) * 1024 + 512 + cg * 64 + cq;
  uint4 h0, h1, l0, l1;
  h0 = *(const uint4*)&oth[nl][cq];     h1 = *(const uint4*)&oth[nl][cq + 8];
  l0 = *(const uint4*)&otl[nl][cq];     l1 = *(const uint4*)&otl[nl][cq + 8];
  *(uint4*)&XHh[xbase] = h0;  *(uint4*)&XHh[xbase + 8] = h1;
  *(uint4*)&XHl[xbase] = l0;  *(uint4*)&XHl[xbase + 8] = l1;
}

// ---------------------------------------------------------------------------
// tail_kernel: blocks 0..511 = [optional dist] + softmax (2 SH rows/block);
//              blocks 512..2559 = threefry rng (present only when do_rng).
// Pt == nullptr -> head mode (softmax only, no SH update).
// ---------------------------------------------------------------------------
__global__ __launch_bounds__(256) void tail_kernel(
    float* __restrict__ SH, const float* __restrict__ Pt,
    const float* __restrict__ b1, const float* __restrict__ w2,
    const float* __restrict__ b2,
    u16* __restrict__ STh, u16* __restrict__ STl,
    u16* __restrict__ RsTh, u16* __restrict__ RsTl,
    u16* __restrict__ XHh, u16* __restrict__ XHl,
    float* __restrict__ outp, int do_rng, u32 k0, u32 k1) {
  int bid = blockIdx.x;
  int tid = threadIdx.x;
  if (bid < 512) {
    int rl = tid >> 7;                  // row-local 0/1
    int t = tid & 127;
    int bs = bid * 2 + rl;              // s-node global id
    int gg = bs >> 7, s = bs & 127;
    float val = SH[bs * 128 + t];
    if (Pt) {
      __shared__ float arow[2][128], w2s[128];
      arow[rl][t] = Pt[(size_t)t * 2048 + bs] + b1[t];   // t plays h here
      if (tid < 128) w2s[tid] = w2[tid];
      __syncthreads();
      const float* pt = Pt + 1024 + gg * 128 + t;
      float acc = 0.f;
#pragma unroll 8
      for (int h = 0; h < 128; ++h) {
        float pv = pt[(size_t)h * 2048];                 // coalesced across t
        acc += fmaxf(arow[rl][h] - pv, 0.f) * w2s[h];
      }
      val += acc + b2[0];
      SH[bs * 128 + t] = val;
    }
    // softmax across the 128 threads of this row (2 waves)
    float m = val;
#pragma unroll
    for (int off = 32; off > 0; off >>= 1) m = fmaxf(m, __shfl_xor(m, off));
    __shared__ float redm[4], reds[4];
    int wv = tid >> 6;
    if ((tid & 63) == 0) redm[wv] = m;
    __syncthreads();
    m = fmaxf(redm[wv], redm[wv ^ 1]);
    float e = expf(val - m);
    float su = e;
#pragma unroll
    for (int off = 32; off > 0; off >>= 1) su += __shfl_xor(su, off);
    if ((tid & 63) == 0) reds[wv] = su;
    __syncthreads();
    su = reds[wv] + reds[wv ^ 1];
    float p = e / su;
    u16 h, lo;
    split2(p, h, lo);
    STh[(gg * 128 + t) * 128 + s] = h;
    STl[(gg * 128 + t) * 128 + s] = lo;
    if (outp) outp[bs * 128 + t] = p;
  } else if (do_rng) {
    u32 j = (u32)(bid - 512) * 256 + tid;        // 0..524287 (= threefry ctr)
    u32 o0, o1;
    tf2x32(k0, k1, 0u, j, o0, o1);
    float val = bits_to_normal(o0 ^ o1);
    u32 node = j >> 9, ch = j & 511;
    u16 h, lo;
    split2(val, h, lo);
    XHh[node * 1024 + ch] = h;
    XHl[node * 1024 + ch] = lo;
    RsTh[ch * 1024 + node] = h;                  // scattered 2B (accepted)
    RsTl[ch * 1024 + node] = lo;
  }
}

// ---------------------------------------------------------------------------
extern "C" void kernel_launch(void* const* d_in, const int* in_sizes, int n_in,
                              void* d_out, int out_size, void* d_ws, size_t ws_size,
                              hipStream_t stream) {
  const float* x_s = (const float*)d_in[0];
  const int* ei_s = (const int*)d_in[1];
  const float* x_t = (const float*)d_in[4];
  const int* ei_t = (const int*)d_in[5];
  const float* e_lin1 = (const float*)d_in[8];
  const float* e_lin2 = (const float*)d_in[9];
  const float* e_rw = (const float*)d_in[10];
  const float* e_rb = (const float*)d_in[11];
  const float* e_g = (const float*)d_in[12];
  const float* e_b = (const float*)d_in[13];
  const float* e_fw = (const float*)d_in[14];
  const float* e_fb = (const float*)d_in[15];
  const float* c_lin1 = (const float*)d_in[16];
  const float* c_lin2 = (const float*)d_in[17];
  const float* c_rw = (const float*)d_in[18];
  const float* c_rb = (const float*)d_in[19];
  const float* c_g = (const float*)d_in[20];
  const float* c_b = (const float*)d_in[21];
  const float* c_fw = (const float*)d_in[22];
  const float* c_fb = (const float*)d_in[23];
  const float* m_w1 = (const float*)d_in[24];
  const float* m_b1 = (const float*)d_in[25];
  const float* m_w2 = (const float*)d_in[26];
  const float* m_b2 = (const float*)d_in[27];
  float* out = (float*)d_out;
  float* ws = (float*)d_ws;

  // workspace (float slots). total ~11.70M floats ~= 46.8 MB
  u16* Mch   = (u16*)(ws + 0);             // [16][128][256]
  u16* Mcl   = (u16*)(ws + 262144);
  u16* Yth   = (u16*)(ws + 524288);        // [1536][2048]
  u16* Ytl   = (u16*)(ws + 2097152);
  float* AGGt = ws + 3670016;              // [512][2048] fp32 (relu'd h)
  u16* XHh   = (u16*)(ws + 4718592);       // [2048][1024]
  u16* XHl   = (u16*)(ws + 5767168);
  u16* WTeh  = (u16*)(ws + 6815744);       // [1536][512]
  u16* WTel  = (u16*)(ws + 7208960);
  u16* WTch  = (u16*)(ws + 7602176);
  u16* WTcl  = (u16*)(ws + 7995392);
  u16* FTeh  = (u16*)(ws + 8388608);       // [512][1024]
  u16* FTel  = (u16*)(ws + 8650752);
  u16* FmTh  = (u16*)(ws + 8912896);       // [128][1024]
  u16* FmTl  = (u16*)(ws + 8978432);
  u16* Oh    = (u16*)(ws + 9043968);       // [2048][512]
  u16* Ol    = (u16*)(ws + 9568256);
  u16* RsTh  = (u16*)(ws + 10092544);      // [512][1024]
  u16* RsTl  = (u16*)(ws + 10354688);
  u16* STh   = (u16*)(ws + 10616832);      // [8][128][128]
  u16* STl   = (u16*)(ws + 10682368);
  float* SH  = ws + 10747904;              // [8][128][128]
  float* Wstage = ws + 10878976;           // [1024][128] Fm staging
  float* Pt  = ws + 11010048;              // [128][2048] fp32 (split-K target)
  float* fbm = ws + 11665408;              // [128]
  float* partS = ws + 11665536;            // [2048]
  float* partQ = ws + 11667584;            // [2048]
  int* Acnt  = (int*)Yth;                  // setup-only alias into Yt region
  int* degd  = Acnt + 262144;
  int* degs  = degd + 2048;

  hipMemsetAsync(Acnt, 0, (262144 + 4096) * sizeof(int), stream);
  count_kernel<<<128, 256, 0, stream>>>(ei_s, ei_t, Acnt, degd, degs);
  norm_adj_kernel<<<2048, 256, 0, stream>>>(Acnt, degd, degs, Mch, Mcl);
  convert_packed<<<3072, 256, 0, stream>>>(e_lin1, e_lin2, e_rw, WTeh, WTel);
  convert_packed<<<3072, 256, 0, stream>>>(c_lin1, c_lin2, c_rw, WTch, WTcl);
  convert_wT<<<2048, 256, 0, stream>>>(e_fw, FTeh, FTel, 1024, 512);
  gemm_f32<<<dim3(2, 16, 1), 256, 0, stream>>>(1024, 128, 512, c_fw, 512,
                                               m_w1, 128, Wstage, 128);
  convert_wT<<<512, 256, 0, stream>>>(Wstage, FmTh, FmTl, 1024, 128);
  fbm_kernel<<<1, 128, 0, stream>>>(c_fb, m_w1, m_b1, fbm);
  copyx_kernel<<<1024, 256, 0, stream>>>(x_s, x_t, XHh, XHl);

  // ---- embedding GNN ----
  mfma_gemm_big<0><<<dim3(12, 16), 512, 0, stream>>>(
      512, XHh, XHl, 1024, WTeh, WTel, 512, Yth, Ytl, 2048, nullptr,
      partS, partQ, Pt);
  // agg_fused: AGGt = relu(Mcat@[Y1;Y2] + Yright + rb)^T, + LN stats
  mfma_gemm<0, 0, 0, 1, 1, 0><<<dim3(8, 2, 16), 256, 0, stream>>>(
      256, Mch, Mcl, 256, 32768, Yth, Ytl, 2048, 128,
      AGGt, nullptr, nullptr, 2048, 128, nullptr,
      Yth, Ytl, e_rb, partS, partQ);
  ln_apply<<<dim3(8, 32), 256, 0, stream>>>(AGGt, partS, partQ, e_g, e_b,
                                            XHh, XHl);
  // O = XH @ Fw + Fb, node-major planes via swapped operands (A=FwT, B=XH)
  mfma_gemm_big<1><<<dim3(16, 4), 512, 0, stream>>>(
      1024, FTeh, FTel, 1024, XHh, XHl, 1024, Oh, Ol, 512, e_fb,
      partS, partQ, Pt);
  // SH[g][s][t] = (Ht @ Hs^T)^T (batched 8)
  mfma_gemm<0, 0, 0, 0, 0, 0><<<dim3(2, 2, 8), 256, 0, stream>>>(
      512, Oh + 1024 * 512, Ol + 1024 * 512, 512, 128 * 512,
      Oh, Ol, 512, 128 * 512,
      SH, nullptr, nullptr, 128, 16384, nullptr,
      nullptr, nullptr, nullptr, nullptr, nullptr);

  // head: S_0 = softmax(SH) -> out + ST planes; rng for t=0
  {
    uint32_t fk0, fk1;
    tf2x32(0u, 42u, 0u, 0u, fk0, fk1);
    tail_kernel<<<2560, 256, 0, stream>>>(SH, nullptr, m_b1, m_w2, m_b2,
                                          STh, STl, RsTh, RsTl, XHh, XHl,
                                          out, 1, fk0, fk1);
  }

  for (int t = 0; t < 10; ++t) {
    // R_t^T flow: D = RsT @ ST^T -> DT[t][ch] = R_t node-major into XH planes
    mfma_gemm<1, 0, 0, 0, 0, 0><<<dim3(2, 8, 8), 256, 0, stream>>>(
        128, RsTh, RsTl, 1024, 128, STh, STl, 128, 16384,
        nullptr, XHh + 1024 * 1024, XHl + 1024 * 1024, 1024, 128 * 1024, nullptr,
        nullptr, nullptr, nullptr, nullptr, nullptr);
    // GNN (common weights); zeroes partS/partQ/Pt for agg_fused + split-K P
    mfma_gemm_big<0><<<dim3(12, 16), 512, 0, stream>>>(
        512, XHh, XHl, 1024, WTch, WTcl, 512, Yth, Ytl, 2048, nullptr,
        partS, partQ, Pt);
    mfma_gemm<0, 0, 0, 1, 1, 0><<<dim3(8, 2, 16), 256, 0, stream>>>(
        256, Mch, Mcl, 256, 32768, Yth, Ytl, 2048, 128,
        AGGt, nullptr, nullptr, 2048, 128, nullptr,
        Yth, Ytl, c_rb, partS, partQ);
    ln_apply<<<dim3(8, 32), 256, 0, stream>>>(AGGt, partS, partQ, c_g, c_b,
                                              XHh, XHl);
    // P^T = (XH @ Fm + fbm)^T, split-K x4 atomic (Pt pre-zeroed by G1);
    // R8 fix: BIASN=1 (bias[h]=fbm), applied on chunk g==0 only.
    mfma_gemm<0, 1, 0, 0, 0, 1><<<dim3(2, 32, 4), 256, 0, stream>>>(
        256, XHh, XHl, 1024, 256, FmTh, FmTl, 1024, 256,
        Pt, nullptr, nullptr, 2048, 0, fbm,
        nullptr, nullptr, nullptr, nullptr, nullptr);
    // tail: dist + softmax -> ST(t+1); rng(t+1) unless last; final writes S_L
    uint32_t fk0, fk1;
    tf2x32(0u, 42u, 0u, (uint32_t)(t + 1), fk0, fk1);
    int do_rng = (t < 9) ? 1 : 0;
    tail_kernel<<<do_rng ? 2560 : 512, 256, 0, stream>>>(
        SH, Pt, m_b1, m_w2, m_b2, STh, STl, RsTh, RsTl, XHh, XHl,
        (t == 9) ? (out + 131072) : nullptr, do_rng, fk0, fk1);
  }
}

// Round 9
// 858.040 us; speedup vs baseline: 1.2955x; 1.2955x over previous
//
#include <hip/hip_runtime.h>
#include <stdint.h>

// ---------------------------------------------------------------------------
// KeypointMatchingModel: B=8, N=128, C_IN=C_OUT=512, H_MLP=128, STEPS=10.
// R2 fp32 2254 | R3 1475 | R4 1890(bug) | R5 1022 (best) | R6 1040 | R8 1111
// (fusion+atomics regressed). R9 = R5 structure + algebraic FLOP cut:
//   R_t = S^T R_s  =>  R_t @ W = S^T (R_s @ W). So:
//   - Ys = R_s @ [Wcat | Fm_left]  (1024x1664x512) -> Yext cols 0..1023
//   - Tmix_b = S_b^T @ Ys_b (batched 8, 128x1664x128) -> Yext cols 1024..2047
//     (fills t-side of Y AND t-side of P_R; R_t GEMM + RsT scatter eliminated)
//   - P = h @ Fm_right + P_R(stored in Yext rows 1536..1663) + fbm  (K=512)
//   MFMA work/iter 13.3 -> 8.9 GF; kernels/iter still 8 (R5-proven set:
//   separate ln_stats/ln_apply, fp32 Pt, no atomics).
// RNG: jax threefry partitionable, bits = o0^o1 of block(key, 0, i). VERIFIED.
// ---------------------------------------------------------------------------

typedef unsigned short u16;
typedef unsigned int u32;
typedef __attribute__((ext_vector_type(8))) short short8;
typedef __attribute__((ext_vector_type(4))) float f32x4;

__device__ inline u16 f2bf(float x) {
  u32 u = __float_as_uint(x);
  u32 r = (u + 0x7fffu + ((u >> 16) & 1u)) >> 16;  // round-nearest-even
  return (u16)r;
}
__device__ inline float bf2f(u16 h) { return __uint_as_float(((u32)h) << 16); }
__device__ inline void split2(float x, u16& h, u16& l) {
  h = f2bf(x);
  l = f2bf(x - bf2f(h));
}

__host__ __device__ inline void tf2x32(uint32_t k0, uint32_t k1, uint32_t x0,
                                       uint32_t x1, uint32_t& o0, uint32_t& o1) {
  uint32_t ks0 = k0, ks1 = k1, ks2 = 0x1BD11BDAu ^ k0 ^ k1;
  x0 += ks0; x1 += ks1;
#define TF_R(r) { x0 += x1; x1 = (x1 << r) | (x1 >> (32 - r)); x1 ^= x0; }
  TF_R(13) TF_R(15) TF_R(26) TF_R(6)   x0 += ks1; x1 += ks2 + 1u;
  TF_R(17) TF_R(29) TF_R(16) TF_R(24)  x0 += ks2; x1 += ks0 + 2u;
  TF_R(13) TF_R(15) TF_R(26) TF_R(6)   x0 += ks0; x1 += ks1 + 3u;
  TF_R(17) TF_R(29) TF_R(16) TF_R(24)  x0 += ks1; x1 += ks2 + 4u;
  TF_R(13) TF_R(15) TF_R(26) TF_R(6)   x0 += ks2; x1 += ks0 + 5u;
#undef TF_R
  o0 = x0; o1 = x1;
}

__device__ inline float erfinv_f(float x) {  // XLA ErfInv32 (Giles)
  float w = -log1pf(-x * x);
  float p;
  if (w < 5.0f) {
    w = w - 2.5f;
    p = 2.81022636e-08f;
    p = fmaf(p, w, 3.43273939e-07f);
    p = fmaf(p, w, -3.5233877e-06f);
    p = fmaf(p, w, -4.39150654e-06f);
    p = fmaf(p, w, 0.00021858087f);
    p = fmaf(p, w, -0.00125372503f);
    p = fmaf(p, w, -0.00417768164f);
    p = fmaf(p, w, 0.246640727f);
    p = fmaf(p, w, 1.50140941f);
  } else {
    w = sqrtf(w) - 3.0f;
    p = -0.000200214257f;
    p = fmaf(p, w, 0.000100950558f);
    p = fmaf(p, w, 0.00134934322f);
    p = fmaf(p, w, -0.00367342844f);
    p = fmaf(p, w, 0.00573950773f);
    p = fmaf(p, w, -0.0076224613f);
    p = fmaf(p, w, 0.00943887047f);
    p = fmaf(p, w, 1.00167406f);
    p = fmaf(p, w, 2.83297682f);
  }
  return p * x;
}

__device__ inline float bits_to_normal(uint32_t bits) {
  uint32_t fb = (bits >> 9) | 0x3f800000u;
  float f = __uint_as_float(fb) - 1.0f;
  float u = f * 2.0f + (-0.99999994f);
  u = fmaxf(-0.99999994f, u);
  return 1.41421356f * erfinv_f(u);
}

// ---------------------------------------------------------------------------
// 64x64-tile split-bf16 MFMA GEMM. D = A @ B^T (A:[M][K], B:[N][K] hi/lo
// planes); stores D^T. OUTP: bf16-plane out; AGGB: Yext-gather B; PADD:
// epilogue adds bf16-plane pair at Padh/Padl[n*2048 + m] (P_R term).
// ---------------------------------------------------------------------------
template <int OUTP, int BIASN, int BIASM, int AGGB, int PADD>
__global__ __launch_bounds__(256) void mfma_gemm(
    int K,
    const u16* __restrict__ Ah, const u16* __restrict__ Al, int lda, int sA,
    const u16* __restrict__ Bh, const u16* __restrict__ Bl, int ldb, int sB,
    float* __restrict__ Cf, u16* __restrict__ Ch, u16* __restrict__ Cl,
    int ldc, int sC, const float* __restrict__ bias,
    const u16* __restrict__ Padh, const u16* __restrict__ Padl) {
  const int g = blockIdx.z;
  Ah += (size_t)g * sA; Al += (size_t)g * sA;
  Bh += (size_t)g * sB; Bl += (size_t)g * sB;
  if (OUTP) { Ch += (size_t)g * sC; Cl += (size_t)g * sC; }
  else { Cf += (size_t)g * sC; }
  __shared__ u16 As[2][64][64];
  __shared__ u16 Bs[2][64][64];
  const int tid = threadIdx.x;
  const int m0 = blockIdx.y * 64, n0 = blockIdx.x * 64;
  const int l = tid & 63;
  const int w = tid >> 6;
  const int wr = (w >> 1) * 32, wc = (w & 1) * 32;
  const int l15 = l & 15, lq = l >> 4;
  f32x4 acc[2][2] = {};
  const int sr = tid >> 3, sc = tid & 7;
  for (int k0 = 0; k0 < K; k0 += 64) {
    __syncthreads();
#pragma unroll
    for (int p = 0; p < 2; ++p) {
      int r = sr + p * 32;
      int dst = (sc ^ (r & 7)) * 8;
      *(uint4*)&As[0][r][dst] = *(const uint4*)&Ah[(size_t)(m0 + r) * lda + k0 + sc * 8];
      *(uint4*)&As[1][r][dst] = *(const uint4*)&Al[(size_t)(m0 + r) * lda + k0 + sc * 8];
      size_t boff;
      if (AGGB) {
        int rowg = (k0 < 128) ? (n0 + r) : (512 + n0 + r);
        boff = (size_t)rowg * ldb + (k0 & 127) + sc * 8;
      } else {
        boff = (size_t)(n0 + r) * ldb + k0 + sc * 8;
      }
      *(uint4*)&Bs[0][r][dst] = *(const uint4*)&Bh[boff];
      *(uint4*)&Bs[1][r][dst] = *(const uint4*)&Bl[boff];
    }
    __syncthreads();
#pragma unroll
    for (int kk = 0; kk < 2; ++kk) {
      short8 aH[2], aL[2], bH[2], bL[2];
#pragma unroll
      for (int i = 0; i < 2; ++i) {
        int mr = wr + i * 16 + l15;
        int ca = ((kk * 4 + lq) ^ (mr & 7)) * 8;
        aH[i] = *(const short8*)&As[0][mr][ca];
        aL[i] = *(const short8*)&As[1][mr][ca];
        int nr = wc + i * 16 + l15;
        int cb = ((kk * 4 + lq) ^ (nr & 7)) * 8;
        bH[i] = *(const short8*)&Bs[0][nr][cb];
        bL[i] = *(const short8*)&Bs[1][nr][cb];
      }
#pragma unroll
      for (int i = 0; i < 2; ++i)
#pragma unroll
        for (int j = 0; j < 2; ++j) {
          acc[i][j] = __builtin_amdgcn_mfma_f32_16x16x32_bf16(aH[i], bH[j], acc[i][j], 0, 0, 0);
          acc[i][j] = __builtin_amdgcn_mfma_f32_16x16x32_bf16(aL[i], bH[j], acc[i][j], 0, 0, 0);
          acc[i][j] = __builtin_amdgcn_mfma_f32_16x16x32_bf16(aH[i], bL[j], acc[i][j], 0, 0, 0);
        }
    }
  }
#pragma unroll
  for (int i = 0; i < 2; ++i)
#pragma unroll
    for (int j = 0; j < 2; ++j) {
      int n = n0 + wc + j * 16 + l15;
      int mb = m0 + wr + i * 16 + lq * 4;
      f32x4 v = acc[i][j];
      if (BIASN) {
        float b = bias[n];
        v[0] += b; v[1] += b; v[2] += b; v[3] += b;
      }
      if (BIASM) {
        f32x4 bb = *(const f32x4*)&bias[mb];
        v[0] += bb[0]; v[1] += bb[1]; v[2] += bb[2]; v[3] += bb[3];
      }
      if (PADD) {
        uint2 ph = *(const uint2*)&Padh[(size_t)n * 2048 + mb];
        uint2 pl = *(const uint2*)&Padl[(size_t)n * 2048 + mb];
        v[0] += bf2f((u16)(ph.x & 0xffff)) + bf2f((u16)(pl.x & 0xffff));
        v[1] += bf2f((u16)(ph.x >> 16)) + bf2f((u16)(pl.x >> 16));
        v[2] += bf2f((u16)(ph.y & 0xffff)) + bf2f((u16)(pl.y & 0xffff));
        v[3] += bf2f((u16)(ph.y >> 16)) + bf2f((u16)(pl.y >> 16));
      }
      if (OUTP) {
        u16 h[4], lo[4];
        split2(v[0], h[0], lo[0]); split2(v[1], h[1], lo[1]);
        split2(v[2], h[2], lo[2]); split2(v[3], h[3], lo[3]);
        uint2 hv = {(u32)h[0] | ((u32)h[1] << 16), (u32)h[2] | ((u32)h[3] << 16)};
        uint2 lv = {(u32)lo[0] | ((u32)lo[1] << 16), (u32)lo[2] | ((u32)lo[3] << 16)};
        *(uint2*)&Ch[(size_t)n * ldc + mb] = hv;
        *(uint2*)&Cl[(size_t)n * ldc + mb] = lv;
      } else {
        *(f32x4*)&Cf[(size_t)n * ldc + mb] = v;
      }
    }
}

// ---------------- setup kernels ---------------------------------------------
__global__ __launch_bounds__(256) void count_kernel(const int* __restrict__ ei_s,
                                                    const int* __restrict__ ei_t,
                                                    int* __restrict__ Acnt,
                                                    int* __restrict__ degd,
                                                    int* __restrict__ degs) {
  int e = blockIdx.x * 256 + threadIdx.x;        // 32768
  int side = e >> 14, idx = e & 16383;
  const int* ei = side ? ei_t : ei_s;
  int src = ei[idx], dst = ei[16384 + idx];
  int g = (dst >> 7) + side * 8;                 // 0..15
  int dl = dst & 127, sl = src & 127;
  atomicAdd(&Acnt[(g * 128 + dl) * 128 + sl], 1);
  atomicAdd(&degd[g * 128 + dl], 1);
  atomicAdd(&degs[g * 128 + sl], 1);
}

__global__ __launch_bounds__(256) void norm_adj_kernel(const int* __restrict__ Acnt,
                                                       const int* __restrict__ degd,
                                                       const int* __restrict__ degs,
                                                       u16* __restrict__ Mh,
                                                       u16* __restrict__ Ml) {
  int idx = blockIdx.x * 256 + threadIdx.x;      // 16*128*256
  int g = idx >> 15, m = (idx >> 8) & 127, k = idx & 255;
  float val;
  if (k < 128)
    val = (float)Acnt[(g * 128 + m) * 128 + k] / (float)max(degd[g * 128 + m], 1);
  else
    val = (float)Acnt[(g * 128 + (k - 128)) * 128 + m] / (float)max(degs[g * 128 + m], 1);
  u16 h, lo;
  split2(val, h, lo);
  Mh[idx] = h; Ml[idx] = lo;
}

// [W1|W2|Wr]^T hi/lo planes: Th[n*512+k], n<512->W1, <1024->W2, else Wr
__global__ __launch_bounds__(256) void convert_packed(const float* __restrict__ W1,
                                                      const float* __restrict__ W2,
                                                      const float* __restrict__ Wr,
                                                      u16* __restrict__ Th,
                                                      u16* __restrict__ Tl) {
  int id = blockIdx.x * 256 + threadIdx.x;       // 1536*512
  int n = id >> 9, k = id & 511;
  const float* W = (n < 512) ? W1 : ((n < 1024) ? W2 : Wr);
  float v = W[k * 512 + (n & 511)];
  u16 h, lo;
  split2(v, h, lo);
  Th[id] = h; Tl[id] = lo;
}

// W [K][N] fp32 -> W^T hi/lo [N][K] bf16
__global__ __launch_bounds__(256) void convert_wT(const float* __restrict__ W,
                                                  u16* __restrict__ Th,
                                                  u16* __restrict__ Tl,
                                                  int K, int N) {
  int id = blockIdx.x * 256 + threadIdx.x;
  int k = id / N, n = id - k * N;
  u16 h, lo;
  split2(W[id], h, lo);
  Th[n * K + k] = h;
  Tl[n * K + k] = lo;
}

// Fm [1024][128] fp32 -> WFTc rows 1536..1663 (k<512) and FmTr [128][512] (k>=512)
__global__ __launch_bounds__(256) void fm_split(const float* __restrict__ Fm,
                                                u16* __restrict__ WFTch,
                                                u16* __restrict__ WFTcl,
                                                u16* __restrict__ FmTrh,
                                                u16* __restrict__ FmTrl) {
  int id = blockIdx.x * 256 + threadIdx.x;       // 1024*128
  int k = id >> 7, h = id & 127;
  float v = Fm[k * 128 + h];
  u16 hi, lo;
  split2(v, hi, lo);
  if (k < 512) {
    WFTch[(size_t)(1536 + h) * 512 + k] = hi;
    WFTcl[(size_t)(1536 + h) * 512 + k] = lo;
  } else {
    FmTrh[(size_t)h * 512 + (k - 512)] = hi;
    FmTrl[(size_t)h * 512 + (k - 512)] = lo;
  }
}

// fbm[h] = m_b1[h] + sum_c c_fb[c] * m_w1[c][h]
__global__ __launch_bounds__(128) void fbm_kernel(const float* __restrict__ fb,
                                                  const float* __restrict__ w1,
                                                  const float* __restrict__ b1,
                                                  float* __restrict__ fbm) {
  int h = threadIdx.x;
  float acc = b1[h];
  for (int c = 0; c < 512; ++c) acc = fmaf(fb[c], w1[c * 128 + h], acc);
  fbm[h] = acc;
}

// x_s/x_t -> XH planes (left 512 cols)
__global__ __launch_bounds__(256) void copyx_kernel(const float* __restrict__ xs,
                                                    const float* __restrict__ xt,
                                                    u16* __restrict__ XHh,
                                                    u16* __restrict__ XHl) {
  int idx = blockIdx.x * 256 + threadIdx.x;      // 2048 rows * 128 float4s
  int row = idx >> 7, c4 = (idx & 127) << 2;
  const float* src = (row < 1024) ? (xs + row * 512 + c4)
                                  : (xt + (row - 1024) * 512 + c4);
  float4 v = *(const float4*)src;
  u16 h[4], lo[4];
  split2(v.x, h[0], lo[0]); split2(v.y, h[1], lo[1]);
  split2(v.z, h[2], lo[2]); split2(v.w, h[3], lo[3]);
  uint2 hv = {(u32)h[0] | ((u32)h[1] << 16), (u32)h[2] | ((u32)h[3] << 16)};
  uint2 lv = {(u32)lo[0] | ((u32)lo[1] << 16), (u32)lo[2] | ((u32)lo[3] << 16)};
  *(uint2*)&XHh[row * 1024 + c4] = hv;
  *(uint2*)&XHl[row * 1024 + c4] = lv;
}

// ---------------- fp32 tiled GEMM (setup only: Fm = c_fw @ m_w1) ------------
__global__ __launch_bounds__(256) void gemm_f32(
    int M, int N, int K,
    const float* __restrict__ A, int lda,
    const float* __restrict__ B, int ldb,
    float* __restrict__ C, int ldc) {
  int m0 = blockIdx.y * 64, n0 = blockIdx.x * 64;
  __shared__ float As[16][64];
  __shared__ float Bs[16][64];
  int tid = threadIdx.x;
  int tx = tid & 15, ty = tid >> 4;
  float acc[4][4] = {};
  for (int k0 = 0; k0 < K; k0 += 16) {
    {
      int m_l = tid & 63, k_l = (tid >> 6) << 2;
      float4 av = *(const float4*)&A[(m0 + m_l) * lda + k0 + k_l];
      As[k_l + 0][m_l] = av.x; As[k_l + 1][m_l] = av.y;
      As[k_l + 2][m_l] = av.z; As[k_l + 3][m_l] = av.w;
    }
    {
      int k_l = tid >> 4, n_l = (tid & 15) << 2;
      float4 bv = *(const float4*)&B[(k0 + k_l) * ldb + n0 + n_l];
      *(float4*)&Bs[k_l][n_l] = bv;
    }
    __syncthreads();
#pragma unroll
    for (int kk = 0; kk < 16; ++kk) {
      float4 a4 = *(const float4*)&As[kk][ty << 2];
      float4 b4 = *(const float4*)&Bs[kk][tx << 2];
      float av[4] = {a4.x, a4.y, a4.z, a4.w};
      float bv[4] = {b4.x, b4.y, b4.z, b4.w};
#pragma unroll
      for (int i = 0; i < 4; ++i)
#pragma unroll
        for (int j = 0; j < 4; ++j) acc[i][j] = fmaf(av[i], bv[j], acc[i][j]);
    }
    __syncthreads();
  }
#pragma unroll
  for (int i = 0; i < 4; ++i) {
    int m = m0 + (ty << 2) + i;
    float4 v = {acc[i][0], acc[i][1], acc[i][2], acc[i][3]};
    *(float4*)&C[m * ldc + n0 + (tx << 2)] = v;
  }
}

// ---- relu+LN pass 1: partial sums per (ch-group, node) ---------------------
__global__ __launch_bounds__(256) void ln_stats(
    const u16* __restrict__ Yth, const u16* __restrict__ Ytl,
    const float* __restrict__ AGGt, const float* __restrict__ rb,
    float* __restrict__ partS, float* __restrict__ partQ) {
  int cg = blockIdx.x, ng = blockIdx.y;
  int lane = threadIdx.x & 63, cs = threadIdx.x >> 6;
  int node = ng * 64 + lane;
  float s = 0.f, q = 0.f;
#pragma unroll
  for (int k = 0; k < 16; ++k) {
    int c = cg * 64 + cs * 16 + k;
    size_t yi = (size_t)(1024 + c) * 2048 + node;
    float v = bf2f(Yth[yi]) + bf2f(Ytl[yi]) + rb[c] + AGGt[(size_t)c * 2048 + node];
    v = fmaxf(v, 0.f);
    s += v; q += v * v;
  }
  __shared__ float ls[4][64], lq[4][64];
  ls[cs][lane] = s; lq[cs][lane] = q;
  __syncthreads();
  if (cs == 0) {
    s = ls[0][lane] + ls[1][lane] + ls[2][lane] + ls[3][lane];
    q = lq[0][lane] + lq[1][lane] + lq[2][lane] + lq[3][lane];
    partS[cg * 2048 + node] = s;
    partQ[cg * 2048 + node] = q;
  }
}

// ---- relu+LN pass 2: normalize + LDS-transpose + coalesced XH write --------
__global__ __launch_bounds__(256) void ln_apply(
    const u16* __restrict__ Yth, const u16* __restrict__ Ytl,
    const float* __restrict__ AGGt, const float* __restrict__ partS,
    const float* __restrict__ partQ, const float* __restrict__ rb,
    const float* __restrict__ gam, const float* __restrict__ bet,
    u16* __restrict__ XHh, u16* __restrict__ XHl) {
  int cg = blockIdx.x, ng = blockIdx.y;
  int lane = threadIdx.x & 63, cs = threadIdx.x >> 6;
  int node = ng * 64 + lane;
  float s = 0.f, q = 0.f;
#pragma unroll
  for (int p = 0; p < 8; ++p) {
    s += partS[p * 2048 + node];
    q += partQ[p * 2048 + node];
  }
  float mu = s * (1.f / 512.f);
  float var = q * (1.f / 512.f) - mu * mu;
  float inv = 1.f / sqrtf(var + 1e-5f);
  __shared__ u16 oth[64][66], otl[64][66];   // +2 pad: conflict-free col writes
#pragma unroll
  for (int k = 0; k < 16; ++k) {
    int c = cg * 64 + cs * 16 + k;
    size_t yi = (size_t)(1024 + c) * 2048 + node;
    float v = bf2f(Yth[yi]) + bf2f(Ytl[yi]) + rb[c] + AGGt[(size_t)c * 2048 + node];
    v = fmaxf(v, 0.f);
    float o = (v - mu) * inv * gam[c] + bet[c];
    u16 h, lo;
    split2(o, h, lo);
    oth[lane][cs * 16 + k] = h;
    otl[lane][cs * 16 + k] = lo;
  }
  __syncthreads();
  int nl = threadIdx.x >> 2, cq = (threadIdx.x & 3) * 16;
  size_t xbase = (size_t)(ng * 64 + nl) * 1024 + 512 + cg * 64 + cq;
  uint4 h0, h1, l0, l1;
  h0 = *(const uint4*)&oth[nl][cq];     h1 = *(const uint4*)&oth[nl][cq + 8];
  l0 = *(const uint4*)&otl[nl][cq];     l1 = *(const uint4*)&otl[nl][cq + 8];
  *(uint4*)&XHh[xbase] = h0;  *(uint4*)&XHh[xbase + 8] = h1;
  *(uint4*)&XHl[xbase] = l0;  *(uint4*)&XHl[xbase + 8] = l1;
}

// fused softmax (blocks 0..511, 2 rows each) + threefry rng (blocks 512..2559)
__global__ __launch_bounds__(256) void srk_kernel(
    const float* __restrict__ SH, u16* __restrict__ STh, u16* __restrict__ STl,
    u16* __restrict__ XHh, u16* __restrict__ XHl,
    float* __restrict__ outp, u32 k0, u32 k1) {
  int bid = blockIdx.x;
  int tid = threadIdx.x;
  if (bid < 512) {
    int r = bid * 2 + (tid >> 7);
    int t = tid & 127;
    int gg = r >> 7, s = r & 127;
    float a = SH[r * 128 + t];
    float m = a;
#pragma unroll
    for (int off = 32; off > 0; off >>= 1) m = fmaxf(m, __shfl_xor(m, off));
    __shared__ float red[2][4];
    int wv = tid >> 6;
    if ((tid & 63) == 0) red[0][wv] = m;
    __syncthreads();
    m = fmaxf(red[0][wv], red[0][wv ^ 1]);
    float e = expf(a - m);
    float su = e;
#pragma unroll
    for (int off = 32; off > 0; off >>= 1) su += __shfl_xor(su, off);
    if ((tid & 63) == 0) red[1][wv] = su;
    __syncthreads();
    su = red[1][wv] + red[1][wv ^ 1];
    float p = e / su;
    u16 h, lo;
    split2(p, h, lo);
    STh[(gg * 128 + t) * 128 + s] = h;
    STl[(gg * 128 + t) * 128 + s] = lo;
    if (outp) outp[r * 128 + t] = p;
  } else {
    u32 j = (u32)(bid - 512) * 256 + tid;        // 0..524287 (= threefry ctr)
    u32 o0, o1;
    tf2x32(k0, k1, 0u, j, o0, o1);
    float val = bits_to_normal(o0 ^ o1);
    u32 node = j >> 9, ch = j & 511;
    u16 h, lo;
    split2(val, h, lo);
    XHh[node * 1024 + ch] = h;
    XHl[node * 1024 + ch] = lo;
  }
}

// S_hat[b,s,t] += sum_h relu(Pt[h][s_node] + b1[h] - Pt[h][t_node]) * w2[h] + b2
__global__ __launch_bounds__(128) void dist_kernel(const float* __restrict__ Pt,
                                                   const float* __restrict__ b1,
                                                   const float* __restrict__ w2,
                                                   const float* __restrict__ b2,
                                                   float* __restrict__ SH) {
  int bs = blockIdx.x;       // s-node global id (0..1023)
  int gb = bs >> 7;
  int t = threadIdx.x;       // 128
  __shared__ float arow[128], w2s[128];
  arow[t] = Pt[(size_t)t * 2048 + bs] + b1[t];
  w2s[t] = w2[t];
  __syncthreads();
  const float* pt = Pt + 1024 + gb * 128 + t;
  float acc = 0.f;
#pragma unroll 8
  for (int h = 0; h < 128; ++h) {
    float pv = pt[(size_t)h * 2048];             // coalesced across t
    acc += fmaxf(arow[h] - pv, 0.f) * w2s[h];
  }
  SH[bs * 128 + t] += acc + b2[0];
}

// ---------------------------------------------------------------------------
extern "C" void kernel_launch(void* const* d_in, const int* in_sizes, int n_in,
                              void* d_out, int out_size, void* d_ws, size_t ws_size,
                              hipStream_t stream) {
  const float* x_s = (const float*)d_in[0];
  const int* ei_s = (const int*)d_in[1];
  const float* x_t = (const float*)d_in[4];
  const int* ei_t = (const int*)d_in[5];
  const float* e_lin1 = (const float*)d_in[8];
  const float* e_lin2 = (const float*)d_in[9];
  const float* e_rw = (const float*)d_in[10];
  const float* e_rb = (const float*)d_in[11];
  const float* e_g = (const float*)d_in[12];
  const float* e_b = (const float*)d_in[13];
  const float* e_fw = (const float*)d_in[14];
  const float* e_fb = (const float*)d_in[15];
  const float* c_lin1 = (const float*)d_in[16];
  const float* c_lin2 = (const float*)d_in[17];
  const float* c_rw = (const float*)d_in[18];
  const float* c_rb = (const float*)d_in[19];
  const float* c_g = (const float*)d_in[20];
  const float* c_b = (const float*)d_in[21];
  const float* c_fw = (const float*)d_in[22];
  const float* c_fb = (const float*)d_in[23];
  const float* m_w1 = (const float*)d_in[24];
  const float* m_b1 = (const float*)d_in[25];
  const float* m_w2 = (const float*)d_in[26];
  const float* m_b2 = (const float*)d_in[27];
  float* out = (float*)d_out;
  float* ws = (float*)d_ws;

  // workspace (float slots), total ~11.05M floats ~= 44.2 MB
  u16* Mch   = (u16*)(ws + 0);             // [16][128][256]
  u16* Mcl   = (u16*)(ws + 262144);
  u16* Yth   = (u16*)(ws + 524288);        // Yext [1664][2048]
  u16* Ytl   = (u16*)(ws + 2228224);
  float* AGGt = ws + 3932160;              // [512][2048] fp32
  u16* XHh   = (u16*)(ws + 4980736);       // [2048][1024]
  u16* XHl   = (u16*)(ws + 6029312);
  u16* WTeh  = (u16*)(ws + 7077888);       // [1536][512]
  u16* WTel  = (u16*)(ws + 7471104);
  u16* WFTch = (u16*)(ws + 7864320);       // [1664][512]  (Wcat_c | Fm_left)^T
  u16* WFTcl = (u16*)(ws + 8290304);
  u16* FTeh  = (u16*)(ws + 8716288);       // [512][1024]
  u16* FTel  = (u16*)(ws + 8978432);
  u16* FmTrh = (u16*)(ws + 9240576);       // [128][512]  Fm_right^T
  u16* FmTrl = (u16*)(ws + 9273344);
  u16* Oh    = (u16*)(ws + 9306112);       // [2048][512]
  u16* Ol    = (u16*)(ws + 9830400);
  u16* STh   = (u16*)(ws + 10354688);      // [8][128][128]
  u16* STl   = (u16*)(ws + 10420224);
  float* SH  = ws + 10485760;              // [8][128][128]
  float* Pt  = ws + 10616832;              // [128][2048] fp32
  float* Fm  = ws + 10878976;              // [1024][128] fp32 staging
  float* fbm = ws + 11010048;              // [128]
  float* partS = ws + 11010176;            // [8][2048]
  float* partQ = ws + 11026560;            // [8][2048]
  int* Acnt  = (int*)Yth;                  // setup-only alias into Yt region
  int* degd  = Acnt + 262144;
  int* degs  = degd + 2048;

  hipMemsetAsync(Acnt, 0, (262144 + 4096) * sizeof(int), stream);
  count_kernel<<<128, 256, 0, stream>>>(ei_s, ei_t, Acnt, degd, degs);
  norm_adj_kernel<<<2048, 256, 0, stream>>>(Acnt, degd, degs, Mch, Mcl);
  convert_packed<<<3072, 256, 0, stream>>>(e_lin1, e_lin2, e_rw, WTeh, WTel);
  convert_packed<<<3072, 256, 0, stream>>>(c_lin1, c_lin2, c_rw, WFTch, WFTcl);
  convert_wT<<<2048, 256, 0, stream>>>(e_fw, FTeh, FTel, 1024, 512);
  gemm_f32<<<dim3(2, 16, 1), 256, 0, stream>>>(1024, 128, 512, c_fw, 512,
                                               m_w1, 128, Fm, 128);
  fm_split<<<512, 256, 0, stream>>>(Fm, WFTch, WFTcl, FmTrh, FmTrl);
  fbm_kernel<<<1, 128, 0, stream>>>(c_fb, m_w1, m_b1, fbm);
  copyx_kernel<<<1024, 256, 0, stream>>>(x_s, x_t, XHh, XHl);

  // ---- embedding GNN (R5-proven) ----
  // Yt_e = (XH[:, :512] @ Wcat_e)^T -> Yext rows 0..1535, all 2048 cols
  mfma_gemm<1, 0, 0, 0, 0><<<dim3(24, 32, 1), 256, 0, stream>>>(
      512, XHh, XHl, 1024, 0, WTeh, WTel, 512, 0,
      nullptr, Yth, Ytl, 2048, 0, nullptr, nullptr, nullptr);
  // AGGt = (Mcat @ [Y1;Y2])^T (batched 16)
  mfma_gemm<0, 0, 0, 1, 0><<<dim3(8, 2, 16), 256, 0, stream>>>(
      256, Mch, Mcl, 256, 32768, Yth, Ytl, 2048, 128,
      AGGt, nullptr, nullptr, 2048, 128, nullptr, nullptr, nullptr);
  ln_stats<<<dim3(8, 32), 256, 0, stream>>>(Yth, Ytl, AGGt, e_rb, partS, partQ);
  ln_apply<<<dim3(8, 32), 256, 0, stream>>>(Yth, Ytl, AGGt, partS, partQ,
                                            e_rb, e_g, e_b, XHh, XHl);
  // O = XH @ Fw + Fb (node-major planes, swapped operands)
  mfma_gemm<1, 0, 1, 0, 0><<<dim3(32, 8, 1), 256, 0, stream>>>(
      1024, FTeh, FTel, 1024, 0, XHh, XHl, 1024, 0,
      nullptr, Oh, Ol, 512, 0, e_fb, nullptr, nullptr);
  // SH[g][s][t] = (Ht @ Hs^T)^T (batched 8)
  mfma_gemm<0, 0, 0, 0, 0><<<dim3(2, 2, 8), 256, 0, stream>>>(
      512, Oh + 1024 * 512, Ol + 1024 * 512, 512, 128 * 512,
      Oh, Ol, 512, 128 * 512,
      SH, nullptr, nullptr, 128, 16384, nullptr, nullptr, nullptr);

  // head: S_0 = softmax(SH) -> out + ST planes; rng for t=0
  {
    uint32_t fk0, fk1;
    tf2x32(0u, 42u, 0u, 0u, fk0, fk1);
    srk_kernel<<<2560, 256, 0, stream>>>(SH, STh, STl, XHh, XHl, out, fk0, fk1);
  }

  for (int t = 0; t < 10; ++t) {
    // Ys_ext = (R_s @ [Wcat_c | Fm_l])^T -> Yext rows 0..1663, cols 0..1023
    mfma_gemm<1, 0, 0, 0, 0><<<dim3(26, 16, 1), 256, 0, stream>>>(
        512, XHh, XHl, 1024, 0, WFTch, WFTcl, 512, 0,
        nullptr, Yth, Ytl, 2048, 0, nullptr, nullptr, nullptr);
    // Tmix_b = S_b^T @ Ys_b -> Yext cols 1024 + g*128 + t  (batched 8)
    // A = ST[t][s] (lda 128, sA 16384); B = YsT[c][g*128+s] (ldb 2048, sB 128)
    mfma_gemm<1, 0, 0, 0, 0><<<dim3(26, 2, 8), 256, 0, stream>>>(
        128, STh, STl, 128, 16384, Yth, Ytl, 2048, 128,
        nullptr, Yth + 1024, Ytl + 1024, 2048, 128, nullptr, nullptr, nullptr);
    // agg
    mfma_gemm<0, 0, 0, 1, 0><<<dim3(8, 2, 16), 256, 0, stream>>>(
        256, Mch, Mcl, 256, 32768, Yth, Ytl, 2048, 128,
        AGGt, nullptr, nullptr, 2048, 128, nullptr, nullptr, nullptr);
    ln_stats<<<dim3(8, 32), 256, 0, stream>>>(Yth, Ytl, AGGt, c_rb, partS, partQ);
    ln_apply<<<dim3(8, 32), 256, 0, stream>>>(Yth, Ytl, AGGt, partS, partQ,
                                              c_rb, c_g, c_b, XHh, XHl);
    // P^T = (h @ Fm_r)^T + P_R(Yext rows 1536..1663) + fbm -> Pt fp32
    mfma_gemm<0, 1, 0, 0, 1><<<dim3(2, 32, 1), 256, 0, stream>>>(
        512, XHh + 512, XHl + 512, 1024, 0, FmTrh, FmTrl, 512, 0,
        Pt, nullptr, nullptr, 2048, 0, fbm,
        Yth + (size_t)1536 * 2048, Ytl + (size_t)1536 * 2048);
    dist_kernel<<<1024, 128, 0, stream>>>(Pt, m_b1, m_w2, m_b2, SH);
    // softmax -> ST(t+1); rng(t+1) unless last; final writes S_L
    uint32_t fk0, fk1;
    tf2x32(0u, 42u, 0u, (uint32_t)(t + 1), fk0, fk1);
    srk_kernel<<<(t < 9) ? 2560 : 512, 256, 0, stream>>>(
        SH, STh, STl, XHh, XHl, (t == 9) ? (out + 131072) : nullptr, fk0, fk1);
  }
}

// Round 10
// 840.997 us; speedup vs baseline: 1.3218x; 1.0203x over previous
//
#include <hip/hip_runtime.h>
#include <stdint.h>

// ---------------------------------------------------------------------------
// KeypointMatchingModel: B=8, N=128, C_IN=C_OUT=512, H_MLP=128, STEPS=10.
// R2 2254 | R3 1475 | R5 1022 | R6 1040 | R8 1111 | R9 858 (S^T factorization).
// R10: fold LN into P GEMM epilogue (loop-h is consumed ONLY by P):
//   P = inv*(v@Fg - mu*sg) + cbf + P_R,  Fg = gam*Fm_r, v = relu(agg+Yr+rb).
//   - agg swaps operands (A-side Yext gather) -> node-major v bf16 planes
//     with fused relu epilogue (v reuses Oh/Ol buffers)
//   - ln_stats_v: light 4MB pass -> pSv/pQv[2048]
//   - P GEMM epilogue applies per-node LN affine + P_R + cbf
//   - ln_apply ELIMINATED from loop (24MB+8MB traffic + h quantization).
//   Loop kernels: srk, Ys, Tmix, agg(v), ln_stats_v, P, dist = 7 (was 8).
// Embedding path unchanged (R5-proven) -> Output 0 is a canary.
// RNG: jax threefry partitionable, bits = o0^o1 of block(key, 0, i). VERIFIED.
// ---------------------------------------------------------------------------

typedef unsigned short u16;
typedef unsigned int u32;
typedef __attribute__((ext_vector_type(8))) short short8;
typedef __attribute__((ext_vector_type(4))) float f32x4;

__device__ inline u16 f2bf(float x) {
  u32 u = __float_as_uint(x);
  u32 r = (u + 0x7fffu + ((u >> 16) & 1u)) >> 16;  // round-nearest-even
  return (u16)r;
}
__device__ inline float bf2f(u16 h) { return __uint_as_float(((u32)h) << 16); }
__device__ inline void split2(float x, u16& h, u16& l) {
  h = f2bf(x);
  l = f2bf(x - bf2f(h));
}

__host__ __device__ inline void tf2x32(uint32_t k0, uint32_t k1, uint32_t x0,
                                       uint32_t x1, uint32_t& o0, uint32_t& o1) {
  uint32_t ks0 = k0, ks1 = k1, ks2 = 0x1BD11BDAu ^ k0 ^ k1;
  x0 += ks0; x1 += ks1;
#define TF_R(r) { x0 += x1; x1 = (x1 << r) | (x1 >> (32 - r)); x1 ^= x0; }
  TF_R(13) TF_R(15) TF_R(26) TF_R(6)   x0 += ks1; x1 += ks2 + 1u;
  TF_R(17) TF_R(29) TF_R(16) TF_R(24)  x0 += ks2; x1 += ks0 + 2u;
  TF_R(13) TF_R(15) TF_R(26) TF_R(6)   x0 += ks0; x1 += ks1 + 3u;
  TF_R(17) TF_R(29) TF_R(16) TF_R(24)  x0 += ks1; x1 += ks2 + 4u;
  TF_R(13) TF_R(15) TF_R(26) TF_R(6)   x0 += ks2; x1 += ks0 + 5u;
#undef TF_R
  o0 = x0; o1 = x1;
}

__device__ inline float erfinv_f(float x) {  // XLA ErfInv32 (Giles)
  float w = -log1pf(-x * x);
  float p;
  if (w < 5.0f) {
    w = w - 2.5f;
    p = 2.81022636e-08f;
    p = fmaf(p, w, 3.43273939e-07f);
    p = fmaf(p, w, -3.5233877e-06f);
    p = fmaf(p, w, -4.39150654e-06f);
    p = fmaf(p, w, 0.00021858087f);
    p = fmaf(p, w, -0.00125372503f);
    p = fmaf(p, w, -0.00417768164f);
    p = fmaf(p, w, 0.246640727f);
    p = fmaf(p, w, 1.50140941f);
  } else {
    w = sqrtf(w) - 3.0f;
    p = -0.000200214257f;
    p = fmaf(p, w, 0.000100950558f);
    p = fmaf(p, w, 0.00134934322f);
    p = fmaf(p, w, -0.00367342844f);
    p = fmaf(p, w, 0.00573950773f);
    p = fmaf(p, w, -0.0076224613f);
    p = fmaf(p, w, 0.00943887047f);
    p = fmaf(p, w, 1.00167406f);
    p = fmaf(p, w, 2.83297682f);
  }
  return p * x;
}

__device__ inline float bits_to_normal(uint32_t bits) {
  uint32_t fb = (bits >> 9) | 0x3f800000u;
  float f = __uint_as_float(fb) - 1.0f;
  float u = f * 2.0f + (-0.99999994f);
  u = fmaxf(-0.99999994f, u);
  return 1.41421356f * erfinv_f(u);
}

// ---------------------------------------------------------------------------
// 64x64-tile split-bf16 MFMA GEMM. D = A @ B^T; stores D^T.
// OUTP: bf16-plane out. AGGB/AGGA: Yext-gather on B/A side. PADD: add P_R
// planes. RELUV: epilogue +Yright+rb, relu (node-major v output, OUTP=1).
// LNEP: LN-affine epilogue inv*(acc - mu*sg[n]) + bias[n] (fp32 out).
// ---------------------------------------------------------------------------
template <int OUTP, int BIASN, int BIASM, int AGGB, int PADD, int AGGA,
          int RELUV, int LNEP>
__global__ __launch_bounds__(256) void mfma_gemm(
    int K,
    const u16* __restrict__ Ah, const u16* __restrict__ Al, int lda, int sA,
    const u16* __restrict__ Bh, const u16* __restrict__ Bl, int ldb, int sB,
    float* __restrict__ Cf, u16* __restrict__ Ch, u16* __restrict__ Cl,
    int ldc, int sC, const float* __restrict__ bias,
    const u16* __restrict__ Padh, const u16* __restrict__ Padl,
    const u16* __restrict__ Yrh, const u16* __restrict__ Yrl,
    const float* __restrict__ rbv, const float* __restrict__ pS,
    const float* __restrict__ pQ, const float* __restrict__ sgv) {
  const int g = blockIdx.z;
  Ah += (size_t)g * sA; Al += (size_t)g * sA;
  Bh += (size_t)g * sB; Bl += (size_t)g * sB;
  if (OUTP) { Ch += (size_t)g * sC; Cl += (size_t)g * sC; }
  else { Cf += (size_t)g * sC; }
  __shared__ u16 As[2][64][64];
  __shared__ u16 Bs[2][64][64];
  const int tid = threadIdx.x;
  const int m0 = blockIdx.y * 64, n0 = blockIdx.x * 64;
  const int l = tid & 63;
  const int w = tid >> 6;
  const int wr = (w >> 1) * 32, wc = (w & 1) * 32;
  const int l15 = l & 15, lq = l >> 4;
  f32x4 acc[2][2] = {};
  const int sr = tid >> 3, sc = tid & 7;
  for (int k0 = 0; k0 < K; k0 += 64) {
    __syncthreads();
#pragma unroll
    for (int p = 0; p < 2; ++p) {
      int r = sr + p * 32;
      int dst = (sc ^ (r & 7)) * 8;
      size_t aoff;
      if (AGGA) {
        int rowg = (k0 < 128) ? (m0 + r) : (512 + m0 + r);
        aoff = (size_t)rowg * lda + (k0 & 127) + sc * 8;
      } else {
        aoff = (size_t)(m0 + r) * lda + k0 + sc * 8;
      }
      *(uint4*)&As[0][r][dst] = *(const uint4*)&Ah[aoff];
      *(uint4*)&As[1][r][dst] = *(const uint4*)&Al[aoff];
      size_t boff;
      if (AGGB) {
        int rowg = (k0 < 128) ? (n0 + r) : (512 + n0 + r);
        boff = (size_t)rowg * ldb + (k0 & 127) + sc * 8;
      } else {
        boff = (size_t)(n0 + r) * ldb + k0 + sc * 8;
      }
      *(uint4*)&Bs[0][r][dst] = *(const uint4*)&Bh[boff];
      *(uint4*)&Bs[1][r][dst] = *(const uint4*)&Bl[boff];
    }
    __syncthreads();
#pragma unroll
    for (int kk = 0; kk < 2; ++kk) {
      short8 aH[2], aL[2], bH[2], bL[2];
#pragma unroll
      for (int i = 0; i < 2; ++i) {
        int mr = wr + i * 16 + l15;
        int ca = ((kk * 4 + lq) ^ (mr & 7)) * 8;
        aH[i] = *(const short8*)&As[0][mr][ca];
        aL[i] = *(const short8*)&As[1][mr][ca];
        int nr = wc + i * 16 + l15;
        int cb = ((kk * 4 + lq) ^ (nr & 7)) * 8;
        bH[i] = *(const short8*)&Bs[0][nr][cb];
        bL[i] = *(const short8*)&Bs[1][nr][cb];
      }
#pragma unroll
      for (int i = 0; i < 2; ++i)
#pragma unroll
        for (int j = 0; j < 2; ++j) {
          acc[i][j] = __builtin_amdgcn_mfma_f32_16x16x32_bf16(aH[i], bH[j], acc[i][j], 0, 0, 0);
          acc[i][j] = __builtin_amdgcn_mfma_f32_16x16x32_bf16(aL[i], bH[j], acc[i][j], 0, 0, 0);
          acc[i][j] = __builtin_amdgcn_mfma_f32_16x16x32_bf16(aH[i], bL[j], acc[i][j], 0, 0, 0);
        }
    }
  }
#pragma unroll
  for (int i = 0; i < 2; ++i)
#pragma unroll
    for (int j = 0; j < 2; ++j) {
      int n = n0 + wc + j * 16 + l15;
      int mb = m0 + wr + i * 16 + lq * 4;
      f32x4 v = acc[i][j];
      if (BIASN) {
        float b = bias[n];
        v[0] += b; v[1] += b; v[2] += b; v[3] += b;
      }
      if (BIASM) {
        f32x4 bb = *(const f32x4*)&bias[mb];
        v[0] += bb[0]; v[1] += bb[1]; v[2] += bb[2]; v[3] += bb[3];
      }
      if (LNEP) {
        f32x4 ps = *(const f32x4*)&pS[mb];
        f32x4 pq = *(const f32x4*)&pQ[mb];
        float sgh = sgv[n];
        float cbh = bias[n];
#pragma unroll
        for (int r = 0; r < 4; ++r) {
          float mu = ps[r] * (1.f / 512.f);
          float var = pq[r] * (1.f / 512.f) - mu * mu;
          float inv = 1.f / sqrtf(var + 1e-5f);
          v[r] = inv * (v[r] - mu * sgh) + cbh;
        }
      }
      if (PADD) {
        uint2 ph = *(const uint2*)&Padh[(size_t)n * 2048 + mb];
        uint2 pl = *(const uint2*)&Padl[(size_t)n * 2048 + mb];
        v[0] += bf2f((u16)(ph.x & 0xffff)) + bf2f((u16)(pl.x & 0xffff));
        v[1] += bf2f((u16)(ph.x >> 16)) + bf2f((u16)(pl.x >> 16));
        v[2] += bf2f((u16)(ph.y & 0xffff)) + bf2f((u16)(pl.y & 0xffff));
        v[3] += bf2f((u16)(ph.y >> 16)) + bf2f((u16)(pl.y >> 16));
      }
      if (RELUV) {
        int ngl = g * 128 + n;   // global node
        f32x4 rbq = *(const f32x4*)&rbv[mb];
#pragma unroll
        for (int r = 0; r < 4; ++r) {
          size_t yi = (size_t)(1024 + mb + r) * 2048 + ngl;
          v[r] = fmaxf(v[r] + bf2f(Yrh[yi]) + bf2f(Yrl[yi]) + rbq[r], 0.f);
        }
      }
      if (OUTP) {
        u16 h[4], lo[4];
        split2(v[0], h[0], lo[0]); split2(v[1], h[1], lo[1]);
        split2(v[2], h[2], lo[2]); split2(v[3], h[3], lo[3]);
        uint2 hv = {(u32)h[0] | ((u32)h[1] << 16), (u32)h[2] | ((u32)h[3] << 16)};
        uint2 lv = {(u32)lo[0] | ((u32)lo[1] << 16), (u32)lo[2] | ((u32)lo[3] << 16)};
        *(uint2*)&Ch[(size_t)n * ldc + mb] = hv;
        *(uint2*)&Cl[(size_t)n * ldc + mb] = lv;
      } else {
        *(f32x4*)&Cf[(size_t)n * ldc + mb] = v;
      }
    }
}

// ---------------- setup kernels ---------------------------------------------
__global__ __launch_bounds__(256) void count_kernel(const int* __restrict__ ei_s,
                                                    const int* __restrict__ ei_t,
                                                    int* __restrict__ Acnt,
                                                    int* __restrict__ degd,
                                                    int* __restrict__ degs) {
  int e = blockIdx.x * 256 + threadIdx.x;        // 32768
  int side = e >> 14, idx = e & 16383;
  const int* ei = side ? ei_t : ei_s;
  int src = ei[idx], dst = ei[16384 + idx];
  int g = (dst >> 7) + side * 8;                 // 0..15
  int dl = dst & 127, sl = src & 127;
  atomicAdd(&Acnt[(g * 128 + dl) * 128 + sl], 1);
  atomicAdd(&degd[g * 128 + dl], 1);
  atomicAdd(&degs[g * 128 + sl], 1);
}

__global__ __launch_bounds__(256) void norm_adj_kernel(const int* __restrict__ Acnt,
                                                       const int* __restrict__ degd,
                                                       const int* __restrict__ degs,
                                                       u16* __restrict__ Mh,
                                                       u16* __restrict__ Ml) {
  int idx = blockIdx.x * 256 + threadIdx.x;      // 16*128*256
  int g = idx >> 15, m = (idx >> 8) & 127, k = idx & 255;
  float val;
  if (k < 128)
    val = (float)Acnt[(g * 128 + m) * 128 + k] / (float)max(degd[g * 128 + m], 1);
  else
    val = (float)Acnt[(g * 128 + (k - 128)) * 128 + m] / (float)max(degs[g * 128 + m], 1);
  u16 h, lo;
  split2(val, h, lo);
  Mh[idx] = h; Ml[idx] = lo;
}

// [W1|W2|Wr]^T hi/lo planes: Th[n*512+k], n<512->W1, <1024->W2, else Wr
__global__ __launch_bounds__(256) void convert_packed(const float* __restrict__ W1,
                                                      const float* __restrict__ W2,
                                                      const float* __restrict__ Wr,
                                                      u16* __restrict__ Th,
                                                      u16* __restrict__ Tl) {
  int id = blockIdx.x * 256 + threadIdx.x;       // 1536*512
  int n = id >> 9, k = id & 511;
  const float* W = (n < 512) ? W1 : ((n < 1024) ? W2 : Wr);
  float v = W[k * 512 + (n & 511)];
  u16 h, lo;
  split2(v, h, lo);
  Th[id] = h; Tl[id] = lo;
}

// W [K][N] fp32 -> W^T hi/lo [N][K] bf16
__global__ __launch_bounds__(256) void convert_wT(const float* __restrict__ W,
                                                  u16* __restrict__ Th,
                                                  u16* __restrict__ Tl,
                                                  int K, int N) {
  int id = blockIdx.x * 256 + threadIdx.x;
  int k = id / N, n = id - k * N;
  u16 h, lo;
  split2(W[id], h, lo);
  Th[n * K + k] = h;
  Tl[n * K + k] = lo;
}

// Fm [1024][128] fp32 -> WFTc rows 1536..1663 (k<512, raw) and
// FgT [128][512] (k>=512, times c_g[c]) for the LN-folded P GEMM.
__global__ __launch_bounds__(256) void fm_split(const float* __restrict__ Fm,
                                                const float* __restrict__ cg,
                                                u16* __restrict__ WFTch,
                                                u16* __restrict__ WFTcl,
                                                u16* __restrict__ FgTh,
                                                u16* __restrict__ FgTl) {
  int id = blockIdx.x * 256 + threadIdx.x;       // 1024*128
  int k = id >> 7, h = id & 127;
  float v = Fm[k * 128 + h];
  u16 hi, lo;
  if (k < 512) {
    split2(v, hi, lo);
    WFTch[(size_t)(1536 + h) * 512 + k] = hi;
    WFTcl[(size_t)(1536 + h) * 512 + k] = lo;
  } else {
    split2(v * cg[k - 512], hi, lo);
    FgTh[(size_t)h * 512 + (k - 512)] = hi;
    FgTl[(size_t)h * 512 + (k - 512)] = lo;
  }
}

// sg[h] = sum_c c_g[c]*Fm_r[c][h]; cbf[h] = sum_c c_b[c]*Fm_r[c][h] + m_b1[h]
//         + sum_c c_fb[c]*m_w1[c][h]
__global__ __launch_bounds__(128) void sgcbf_kernel(
    const float* __restrict__ Fm, const float* __restrict__ cg,
    const float* __restrict__ cb, const float* __restrict__ cfb,
    const float* __restrict__ w1, const float* __restrict__ b1,
    float* __restrict__ sg, float* __restrict__ cbf) {
  int h = threadIdx.x;
  float s = 0.f, c2 = 0.f, fb = b1[h];
  for (int c = 0; c < 512; ++c) {
    float fm = Fm[(512 + c) * 128 + h];
    s = fmaf(cg[c], fm, s);
    c2 = fmaf(cb[c], fm, c2);
    fb = fmaf(cfb[c], w1[c * 128 + h], fb);
  }
  sg[h] = s;
  cbf[h] = c2 + fb;
}

// x_s/x_t -> XH planes (left 512 cols)
__global__ __launch_bounds__(256) void copyx_kernel(const float* __restrict__ xs,
                                                    const float* __restrict__ xt,
                                                    u16* __restrict__ XHh,
                                                    u16* __restrict__ XHl) {
  int idx = blockIdx.x * 256 + threadIdx.x;      // 2048 rows * 128 float4s
  int row = idx >> 7, c4 = (idx & 127) << 2;
  const float* src = (row < 1024) ? (xs + row * 512 + c4)
                                  : (xt + (row - 1024) * 512 + c4);
  float4 v = *(const float4*)src;
  u16 h[4], lo[4];
  split2(v.x, h[0], lo[0]); split2(v.y, h[1], lo[1]);
  split2(v.z, h[2], lo[2]); split2(v.w, h[3], lo[3]);
  uint2 hv = {(u32)h[0] | ((u32)h[1] << 16), (u32)h[2] | ((u32)h[3] << 16)};
  uint2 lv = {(u32)lo[0] | ((u32)lo[1] << 16), (u32)lo[2] | ((u32)lo[3] << 16)};
  *(uint2*)&XHh[row * 1024 + c4] = hv;
  *(uint2*)&XHl[row * 1024 + c4] = lv;
}

// ---------------- fp32 tiled GEMM (setup only: Fm = c_fw @ m_w1) ------------
__global__ __launch_bounds__(256) void gemm_f32(
    int M, int N, int K,
    const float* __restrict__ A, int lda,
    const float* __restrict__ B, int ldb,
    float* __restrict__ C, int ldc) {
  int m0 = blockIdx.y * 64, n0 = blockIdx.x * 64;
  __shared__ float As[16][64];
  __shared__ float Bs[16][64];
  int tid = threadIdx.x;
  int tx = tid & 15, ty = tid >> 4;
  float acc[4][4] = {};
  for (int k0 = 0; k0 < K; k0 += 16) {
    {
      int m_l = tid & 63, k_l = (tid >> 6) << 2;
      float4 av = *(const float4*)&A[(m0 + m_l) * lda + k0 + k_l];
      As[k_l + 0][m_l] = av.x; As[k_l + 1][m_l] = av.y;
      As[k_l + 2][m_l] = av.z; As[k_l + 3][m_l] = av.w;
    }
    {
      int k_l = tid >> 4, n_l = (tid & 15) << 2;
      float4 bv = *(const float4*)&B[(k0 + k_l) * ldb + n0 + n_l];
      *(float4*)&Bs[k_l][n_l] = bv;
    }
    __syncthreads();
#pragma unroll
    for (int kk = 0; kk < 16; ++kk) {
      float4 a4 = *(const float4*)&As[kk][ty << 2];
      float4 b4 = *(const float4*)&Bs[kk][tx << 2];
      float av[4] = {a4.x, a4.y, a4.z, a4.w};
      float bv[4] = {b4.x, b4.y, b4.z, b4.w};
#pragma unroll
      for (int i = 0; i < 4; ++i)
#pragma unroll
        for (int j = 0; j < 4; ++j) acc[i][j] = fmaf(av[i], bv[j], acc[i][j]);
    }
    __syncthreads();
  }
#pragma unroll
  for (int i = 0; i < 4; ++i) {
    int m = m0 + (ty << 2) + i;
    float4 v = {acc[i][0], acc[i][1], acc[i][2], acc[i][3]};
    *(float4*)&C[m * ldc + n0 + (tx << 2)] = v;
  }
}

// ---- embedding relu+LN pass 1 (R5-proven) ----------------------------------
__global__ __launch_bounds__(256) void ln_stats(
    const u16* __restrict__ Yth, const u16* __restrict__ Ytl,
    const float* __restrict__ AGGt, const float* __restrict__ rb,
    float* __restrict__ partS, float* __restrict__ partQ) {
  int cg = blockIdx.x, ng = blockIdx.y;
  int lane = threadIdx.x & 63, cs = threadIdx.x >> 6;
  int node = ng * 64 + lane;
  float s = 0.f, q = 0.f;
#pragma unroll
  for (int k = 0; k < 16; ++k) {
    int c = cg * 64 + cs * 16 + k;
    size_t yi = (size_t)(1024 + c) * 2048 + node;
    float v = bf2f(Yth[yi]) + bf2f(Ytl[yi]) + rb[c] + AGGt[(size_t)c * 2048 + node];
    v = fmaxf(v, 0.f);
    s += v; q += v * v;
  }
  __shared__ float ls[4][64], lq[4][64];
  ls[cs][lane] = s; lq[cs][lane] = q;
  __syncthreads();
  if (cs == 0) {
    s = ls[0][lane] + ls[1][lane] + ls[2][lane] + ls[3][lane];
    q = lq[0][lane] + lq[1][lane] + lq[2][lane] + lq[3][lane];
    partS[cg * 2048 + node] = s;
    partQ[cg * 2048 + node] = q;
  }
}

// ---- embedding relu+LN pass 2 (R5-proven) ----------------------------------
__global__ __launch_bounds__(256) void ln_apply(
    const u16* __restrict__ Yth, const u16* __restrict__ Ytl,
    const float* __restrict__ AGGt, const float* __restrict__ partS,
    const float* __restrict__ partQ, const float* __restrict__ rb,
    const float* __restrict__ gam, const float* __restrict__ bet,
    u16* __restrict__ XHh, u16* __restrict__ XHl) {
  int cg = blockIdx.x, ng = blockIdx.y;
  int lane = threadIdx.x & 63, cs = threadIdx.x >> 6;
  int node = ng * 64 + lane;
  float s = 0.f, q = 0.f;
#pragma unroll
  for (int p = 0; p < 8; ++p) {
    s += partS[p * 2048 + node];
    q += partQ[p * 2048 + node];
  }
  float mu = s * (1.f / 512.f);
  float var = q * (1.f / 512.f) - mu * mu;
  float inv = 1.f / sqrtf(var + 1e-5f);
  __shared__ u16 oth[64][66], otl[64][66];   // +2 pad: conflict-free col writes
#pragma unroll
  for (int k = 0; k < 16; ++k) {
    int c = cg * 64 + cs * 16 + k;
    size_t yi = (size_t)(1024 + c) * 2048 + node;
    float v = bf2f(Yth[yi]) + bf2f(Ytl[yi]) + rb[c] + AGGt[(size_t)c * 2048 + node];
    v = fmaxf(v, 0.f);
    float o = (v - mu) * inv * gam[c] + bet[c];
    u16 h, lo;
    split2(o, h, lo);
    oth[lane][cs * 16 + k] = h;
    otl[lane][cs * 16 + k] = lo;
  }
  __syncthreads();
  int nl = threadIdx.x >> 2, cq = (threadIdx.x & 3) * 16;
  size_t xbase = (size_t)(ng * 64 + nl) * 1024 + 512 + cg * 64 + cq;
  uint4 h0, h1, l0, l1;
  h0 = *(const uint4*)&oth[nl][cq];     h1 = *(const uint4*)&oth[nl][cq + 8];
  l0 = *(const uint4*)&otl[nl][cq];     l1 = *(const uint4*)&otl[nl][cq + 8];
  *(uint4*)&XHh[xbase] = h0;  *(uint4*)&XHh[xbase + 8] = h1;
  *(uint4*)&XHl[xbase] = l0;  *(uint4*)&XHl[xbase + 8] = l1;
}

// ---- loop LN stats on node-major v planes [2048][512] ----------------------
__global__ __launch_bounds__(256) void ln_stats_v(
    const u16* __restrict__ vh, const u16* __restrict__ vl,
    float* __restrict__ pSv, float* __restrict__ pQv) {
  int node = blockIdx.x * 8 + (threadIdx.x >> 5);
  int l32 = threadIdx.x & 31;
  size_t base = (size_t)node * 512 + l32 * 16;
  uint4 h0 = *(const uint4*)&vh[base];
  uint4 h1 = *(const uint4*)&vh[base + 8];
  uint4 l0 = *(const uint4*)&vl[base];
  uint4 l1 = *(const uint4*)&vl[base + 8];
  float s = 0.f, q = 0.f;
  u32 hw[8] = {h0.x, h0.y, h0.z, h0.w, h1.x, h1.y, h1.z, h1.w};
  u32 lw[8] = {l0.x, l0.y, l0.z, l0.w, l1.x, l1.y, l1.z, l1.w};
#pragma unroll
  for (int i = 0; i < 8; ++i) {
    float a = bf2f((u16)(hw[i] & 0xffff)) + bf2f((u16)(lw[i] & 0xffff));
    float b = bf2f((u16)(hw[i] >> 16)) + bf2f((u16)(lw[i] >> 16));
    s += a + b;
    q += a * a + b * b;
  }
#pragma unroll
  for (int off = 16; off > 0; off >>= 1) {
    s += __shfl_xor(s, off);
    q += __shfl_xor(q, off);
  }
  if (l32 == 0) { pSv[node] = s; pQv[node] = q; }
}

// fused softmax (blocks 0..511, 2 rows each) + threefry rng (blocks 512..2559)
__global__ __launch_bounds__(256) void srk_kernel(
    const float* __restrict__ SH, u16* __restrict__ STh, u16* __restrict__ STl,
    u16* __restrict__ XHh, u16* __restrict__ XHl,
    float* __restrict__ outp, u32 k0, u32 k1) {
  int bid = blockIdx.x;
  int tid = threadIdx.x;
  if (bid < 512) {
    int r = bid * 2 + (tid >> 7);
    int t = tid & 127;
    int gg = r >> 7, s = r & 127;
    float a = SH[r * 128 + t];
    float m = a;
#pragma unroll
    for (int off = 32; off > 0; off >>= 1) m = fmaxf(m, __shfl_xor(m, off));
    __shared__ float red[2][4];
    int wv = tid >> 6;
    if ((tid & 63) == 0) red[0][wv] = m;
    __syncthreads();
    m = fmaxf(red[0][wv], red[0][wv ^ 1]);
    float e = expf(a - m);
    float su = e;
#pragma unroll
    for (int off = 32; off > 0; off >>= 1) su += __shfl_xor(su, off);
    if ((tid & 63) == 0) red[1][wv] = su;
    __syncthreads();
    su = red[1][wv] + red[1][wv ^ 1];
    float p = e / su;
    u16 h, lo;
    split2(p, h, lo);
    STh[(gg * 128 + t) * 128 + s] = h;
    STl[(gg * 128 + t) * 128 + s] = lo;
    if (outp) outp[r * 128 + t] = p;
  } else {
    u32 j = (u32)(bid - 512) * 256 + tid;        // 0..524287 (= threefry ctr)
    u32 o0, o1;
    tf2x32(k0, k1, 0u, j, o0, o1);
    float val = bits_to_normal(o0 ^ o1);
    u32 node = j >> 9, ch = j & 511;
    u16 h, lo;
    split2(val, h, lo);
    XHh[node * 1024 + ch] = h;
    XHl[node * 1024 + ch] = lo;
  }
}

// S_hat[b,s,t] += sum_h relu(Pt[h][s_node] + b1[h] - Pt[h][t_node]) * w2[h] + b2
__global__ __launch_bounds__(128) void dist_kernel(const float* __restrict__ Pt,
                                                   const float* __restrict__ b1,
                                                   const float* __restrict__ w2,
                                                   const float* __restrict__ b2,
                                                   float* __restrict__ SH) {
  int bs = blockIdx.x;       // s-node global id (0..1023)
  int gb = bs >> 7;
  int t = threadIdx.x;       // 128
  __shared__ float arow[128], w2s[128];
  arow[t] = Pt[(size_t)t * 2048 + bs] + b1[t];
  w2s[t] = w2[t];
  __syncthreads();
  const float* pt = Pt + 1024 + gb * 128 + t;
  float acc = 0.f;
#pragma unroll 8
  for (int h = 0; h < 128; ++h) {
    float pv = pt[(size_t)h * 2048];             // coalesced across t
    acc += fmaxf(arow[h] - pv, 0.f) * w2s[h];
  }
  SH[bs * 128 + t] += acc + b2[0];
}

// ---------------------------------------------------------------------------
extern "C" void kernel_launch(void* const* d_in, const int* in_sizes, int n_in,
                              void* d_out, int out_size, void* d_ws, size_t ws_size,
                              hipStream_t stream) {
  const float* x_s = (const float*)d_in[0];
  const int* ei_s = (const int*)d_in[1];
  const float* x_t = (const float*)d_in[4];
  const int* ei_t = (const int*)d_in[5];
  const float* e_lin1 = (const float*)d_in[8];
  const float* e_lin2 = (const float*)d_in[9];
  const float* e_rw = (const float*)d_in[10];
  const float* e_rb = (const float*)d_in[11];
  const float* e_g = (const float*)d_in[12];
  const float* e_b = (const float*)d_in[13];
  const float* e_fw = (const float*)d_in[14];
  const float* e_fb = (const float*)d_in[15];
  const float* c_lin1 = (const float*)d_in[16];
  const float* c_lin2 = (const float*)d_in[17];
  const float* c_rw = (const float*)d_in[18];
  const float* c_rb = (const float*)d_in[19];
  const float* c_g = (const float*)d_in[20];
  const float* c_b = (const float*)d_in[21];
  const float* c_fw = (const float*)d_in[22];
  const float* c_fb = (const float*)d_in[23];
  const float* m_w1 = (const float*)d_in[24];
  const float* m_b1 = (const float*)d_in[25];
  const float* m_w2 = (const float*)d_in[26];
  const float* m_b2 = (const float*)d_in[27];
  float* out = (float*)d_out;
  float* ws = (float*)d_ws;

  // workspace (float slots), total ~11.05M floats ~= 44.2 MB
  u16* Mch   = (u16*)(ws + 0);             // [16][128][256]
  u16* Mcl   = (u16*)(ws + 262144);
  u16* Yth   = (u16*)(ws + 524288);        // Yext [1664][2048]
  u16* Ytl   = (u16*)(ws + 2228224);
  float* AGGt = ws + 3932160;              // [512][2048] fp32 (embedding)
  u16* XHh   = (u16*)(ws + 4980736);       // [2048][1024]
  u16* XHl   = (u16*)(ws + 6029312);
  u16* WTeh  = (u16*)(ws + 7077888);       // [1536][512]
  u16* WTel  = (u16*)(ws + 7471104);
  u16* WFTch = (u16*)(ws + 7864320);       // [1664][512]  (Wcat_c | Fm_left)^T
  u16* WFTcl = (u16*)(ws + 8290304);
  u16* FTeh  = (u16*)(ws + 8716288);       // [512][1024]
  u16* FTel  = (u16*)(ws + 8978432);
  u16* FgTh  = (u16*)(ws + 9240576);       // [128][512]  (gam*Fm_right)^T
  u16* FgTl  = (u16*)(ws + 9273344);
  u16* Oh    = (u16*)(ws + 9306112);       // [2048][512] (embedding O / loop v)
  u16* Ol    = (u16*)(ws + 9830400);
  u16* STh   = (u16*)(ws + 10354688);      // [8][128][128]
  u16* STl   = (u16*)(ws + 10420224);
  float* SH  = ws + 10485760;              // [8][128][128]
  float* Pt  = ws + 10616832;              // [128][2048] fp32
  float* Fm  = ws + 10878976;              // [1024][128] fp32 staging
  float* sg  = ws + 11010048;              // [128]
  float* cbf = ws + 11010176;              // [128]
  float* partS = ws + 11010304;            // [8][2048] (embedding)
  float* partQ = ws + 11026688;
  float* pSv = ws + 11043072;              // [2048] (loop)
  float* pQv = ws + 11045120;              // ends 11047168
  int* Acnt  = (int*)Yth;                  // setup-only alias into Yt region
  int* degd  = Acnt + 262144;
  int* degs  = degd + 2048;

  hipMemsetAsync(Acnt, 0, (262144 + 4096) * sizeof(int), stream);
  count_kernel<<<128, 256, 0, stream>>>(ei_s, ei_t, Acnt, degd, degs);
  norm_adj_kernel<<<2048, 256, 0, stream>>>(Acnt, degd, degs, Mch, Mcl);
  convert_packed<<<3072, 256, 0, stream>>>(e_lin1, e_lin2, e_rw, WTeh, WTel);
  convert_packed<<<3072, 256, 0, stream>>>(c_lin1, c_lin2, c_rw, WFTch, WFTcl);
  convert_wT<<<2048, 256, 0, stream>>>(e_fw, FTeh, FTel, 1024, 512);
  gemm_f32<<<dim3(2, 16, 1), 256, 0, stream>>>(1024, 128, 512, c_fw, 512,
                                               m_w1, 128, Fm, 128);
  fm_split<<<512, 256, 0, stream>>>(Fm, c_g, WFTch, WFTcl, FgTh, FgTl);
  sgcbf_kernel<<<1, 128, 0, stream>>>(Fm, c_g, c_b, c_fb, m_w1, m_b1, sg, cbf);
  copyx_kernel<<<1024, 256, 0, stream>>>(x_s, x_t, XHh, XHl);

  // ---- embedding GNN (R5-proven) ----
  mfma_gemm<1, 0, 0, 0, 0, 0, 0, 0><<<dim3(24, 32, 1), 256, 0, stream>>>(
      512, XHh, XHl, 1024, 0, WTeh, WTel, 512, 0,
      nullptr, Yth, Ytl, 2048, 0, nullptr, nullptr, nullptr,
      nullptr, nullptr, nullptr, nullptr, nullptr, nullptr);
  mfma_gemm<0, 0, 0, 1, 0, 0, 0, 0><<<dim3(8, 2, 16), 256, 0, stream>>>(
      256, Mch, Mcl, 256, 32768, Yth, Ytl, 2048, 128,
      AGGt, nullptr, nullptr, 2048, 128, nullptr, nullptr, nullptr,
      nullptr, nullptr, nullptr, nullptr, nullptr, nullptr);
  ln_stats<<<dim3(8, 32), 256, 0, stream>>>(Yth, Ytl, AGGt, e_rb, partS, partQ);
  ln_apply<<<dim3(8, 32), 256, 0, stream>>>(Yth, Ytl, AGGt, partS, partQ,
                                            e_rb, e_g, e_b, XHh, XHl);
  mfma_gemm<1, 0, 1, 0, 0, 0, 0, 0><<<dim3(32, 8, 1), 256, 0, stream>>>(
      1024, FTeh, FTel, 1024, 0, XHh, XHl, 1024, 0,
      nullptr, Oh, Ol, 512, 0, e_fb, nullptr, nullptr,
      nullptr, nullptr, nullptr, nullptr, nullptr, nullptr);
  mfma_gemm<0, 0, 0, 0, 0, 0, 0, 0><<<dim3(2, 2, 8), 256, 0, stream>>>(
      512, Oh + 1024 * 512, Ol + 1024 * 512, 512, 128 * 512,
      Oh, Ol, 512, 128 * 512,
      SH, nullptr, nullptr, 128, 16384, nullptr, nullptr, nullptr,
      nullptr, nullptr, nullptr, nullptr, nullptr, nullptr);

  // head: S_0 = softmax(SH) -> out + ST planes; rng for t=0
  {
    uint32_t fk0, fk1;
    tf2x32(0u, 42u, 0u, 0u, fk0, fk1);
    srk_kernel<<<2560, 256, 0, stream>>>(SH, STh, STl, XHh, XHl, out, fk0, fk1);
  }

  for (int t = 0; t < 10; ++t) {
    // Ys_ext = (R_s @ [Wcat_c | Fm_l])^T -> Yext rows 0..1663, cols 0..1023
    mfma_gemm<1, 0, 0, 0, 0, 0, 0, 0><<<dim3(26, 16, 1), 256, 0, stream>>>(
        512, XHh, XHl, 1024, 0, WFTch, WFTcl, 512, 0,
        nullptr, Yth, Ytl, 2048, 0, nullptr, nullptr, nullptr,
        nullptr, nullptr, nullptr, nullptr, nullptr, nullptr);
    // Tmix_b = S_b^T @ Ys_b -> Yext cols 1024 + g*128 + t  (batched 8)
    mfma_gemm<1, 0, 0, 0, 0, 0, 0, 0><<<dim3(26, 2, 8), 256, 0, stream>>>(
        128, STh, STl, 128, 16384, Yth, Ytl, 2048, 128,
        nullptr, Yth + 1024, Ytl + 1024, 2048, 128, nullptr, nullptr, nullptr,
        nullptr, nullptr, nullptr, nullptr, nullptr, nullptr);
    // agg (swapped operands: A = Yext gather, B = Mcat) -> node-major v planes
    // with fused +Yright +rb, relu epilogue. v reuses Oh/Ol.
    mfma_gemm<1, 0, 0, 0, 0, 1, 1, 0><<<dim3(2, 8, 16), 256, 0, stream>>>(
        256, Yth, Ytl, 2048, 128, Mch, Mcl, 256, 32768,
        nullptr, Oh, Ol, 512, 128 * 512, nullptr, nullptr, nullptr,
        Yth, Ytl, c_rb, nullptr, nullptr, nullptr);
    // light LN stats on v
    ln_stats_v<<<256, 256, 0, stream>>>(Oh, Ol, pSv, pQv);
    // P^T = LN-folded: inv*(v@Fg - mu*sg) + cbf + P_R  -> Pt fp32 [128][2048]
    mfma_gemm<0, 0, 0, 0, 1, 0, 0, 1><<<dim3(2, 32, 1), 256, 0, stream>>>(
        512, Oh, Ol, 512, 0, FgTh, FgTl, 512, 0,
        Pt, nullptr, nullptr, 2048, 0, cbf,
        Yth + (size_t)1536 * 2048, Ytl + (size_t)1536 * 2048,
        nullptr, nullptr, nullptr, pSv, pQv, sg);
    dist_kernel<<<1024, 128, 0, stream>>>(Pt, m_b1, m_w2, m_b2, SH);
    // softmax -> ST(t+1); rng(t+1) unless last; final writes S_L
    uint32_t fk0, fk1;
    tf2x32(0u, 42u, 0u, (uint32_t)(t + 1), fk0, fk1);
    srk_kernel<<<(t < 9) ? 2560 : 512, 256, 0, stream>>>(
        SH, STh, STl, XHh, XHl, (t == 9) ? (out + 131072) : nullptr, fk0, fk1);
  }
}